// Round 21
// baseline (1396.146 us; speedup 1.0000x reference)
//
#include <hip/hip_runtime.h>
#include <cmath>

#define HWD 192
#define PIX (HWD*HWD)      // 36864
#define BB  4
#define CCH 128

using short8 = __attribute__((ext_vector_type(8))) short;
using f32x4  = __attribute__((ext_vector_type(4))) float;

__device__ __forceinline__ float gelu_f(float x) {
    return 0.5f * x * (1.0f + erff(x * 0.70710678118654752f));
}
__device__ __forceinline__ unsigned short f2bf(float f) {
    unsigned int u = __float_as_uint(f);
    u += 0x7fff + ((u >> 16) & 1);          // round-to-nearest-even
    return (unsigned short)(u >> 16);
}
__device__ __forceinline__ float bf2f(unsigned short s) {
    return __uint_as_float((unsigned int)s << 16);
}
__device__ __forceinline__ unsigned pack2bf(float a, float b) {
    return (unsigned)f2bf(a) | ((unsigned)f2bf(b) << 16);
}

// ---------------- LayerNorm: fp32 in, bf16 out TRANSPOSED (B,PIX,128) ----------
__global__ __launch_bounds__(256) void ln_t_kernel(const float* __restrict__ in,
        const float* __restrict__ w, const float* __restrict__ b,
        unsigned short* __restrict__ outT)
{
    int t = blockIdx.x * 256 + threadIdx.x;       // BB*PIX threads
    int bi = t / PIX;
    int p  = t - bi*PIX;
    const float* base = in + (size_t)bi * CCH * PIX + p;
    float v[CCH];
    float s = 0.f;
    #pragma unroll
    for (int c=0;c<CCH;++c) { v[c] = base[(size_t)c*PIX]; s += v[c]; }
    float m = s * (1.f/128.f);
    float q = 0.f;
    #pragma unroll
    for (int c=0;c<CCH;++c) { float d = v[c]-m; q += d*d; }
    float iv = rsqrtf(q*(1.f/128.f) + 1e-6f);
    unsigned short* ob = outT + ((size_t)bi * PIX + p) * 128;
    #pragma unroll
    for (int qq=0; qq<16; ++qq) {
        unsigned short e[8];
        #pragma unroll
        for (int j=0;j<8;++j) {
            int c = qq*8 + j;
            e[j] = f2bf((v[c]-m)*iv*w[c] + b[c]);
        }
        *(uint4*)&ob[qq*8] = *(uint4*)e;
    }
}

// ---------------- transpose y ch 0..31: (B,128,PIX) -> (B,PIX,32) --------------
__global__ __launch_bounds__(256) void t32_kernel(const unsigned short* __restrict__ in,
    unsigned short* __restrict__ outT)
{
    int t = blockIdx.x * 256 + threadIdx.x;       // BB*PIX threads
    int bi = t / PIX;
    int p  = t - bi*PIX;
    const unsigned short* base = in + (size_t)bi * CCH * PIX + p;
    unsigned short e[32];
    #pragma unroll
    for (int c=0;c<32;++c) e[c] = base[(size_t)c*PIX];
    unsigned short* ob = outT + ((size_t)bi * PIX + p) * 32;
    #pragma unroll
    for (int q=0;q<4;++q) *(uint4*)&ob[q*8] = *(uint4*)&e[q*8];
}

// ---------------- 1x1 conv via bf16 MFMA ---------------------------------------
// WINPERM (with TRANSIN): stage pixel perm(wk) so output pixel axis is
// window-major (win*256 + k). 1x1 conv is pixel-permutation invariant.
template<typename TIN, bool TRANSIN, bool DOGELU, bool DORES, bool OBF, bool WINPERM>
__global__ __launch_bounds__(256) void conv1x1_mfma_kernel(
    const TIN* __restrict__ in,
    const unsigned short* __restrict__ wq,   // (Cout, Cin) bf16
    const float* __restrict__ bias,
    const float* __restrict__ res,           // (z, Cout, PIX) fp32 or null
    void* __restrict__ outv,                 // (z, Cout, PIX)
    int Cin)
{
    constexpr int CIP = 72;
    __shared__ unsigned short XL[128*CIP];   // 18,432 B
    const int Cout = gridDim.y * 128;
    const int px0 = blockIdx.x * 128;
    const int co0 = blockIdx.y * 128;
    const size_t bi = blockIdx.z;
    in  += bi * (size_t)Cin * PIX;
    if (DORES) res += bi * (size_t)Cout * PIX;
    float* outf = (float*)outv + bi * (size_t)Cout * PIX;
    unsigned short* outb = (unsigned short*)outv + bi * (size_t)Cout * PIX;
    const int tid = threadIdx.x;
    const int lane = tid & 63, wid = tid >> 6;
    const int wco = (wid >> 1) * 64;
    const int wpx = (wid & 1) * 64;
    const int l15 = lane & 15, l4 = lane >> 4;

    f32x4 acc[4][4];
    #pragma unroll
    for (int i=0;i<4;++i)
        #pragma unroll
        for (int j=0;j<4;++j) acc[i][j] = (f32x4){0.f,0.f,0.f,0.f};

    for (int k0 = 0; k0 < Cin; k0 += 64) {
        __syncthreads();
        if constexpr (TRANSIN) {
            #pragma unroll
            for (int it = 0; it < 4; ++it) {
                int idx = tid + it*256;
                int q = idx & 7, pxl = idx >> 3;
                int src;
                if constexpr (WINPERM) {
                    int wk = px0 + pxl;
                    int win = wk >> 8, k = wk & 255;
                    int wy = win / 12, wxw = win - wy*12;
                    src = ((wy<<4) + (k>>4))*HWD + (wxw<<4) + (k&15);
                } else {
                    src = px0 + pxl;
                }
                const uint4 v = *(const uint4*)((const unsigned short*)in
                                + ((size_t)src)*128 + k0 + q*8);
                *(uint4*)&XL[pxl*CIP + q*8] = v;
            }
        } else {
            #pragma unroll
            for (int it = 0; it < 2; ++it) {
                int idx = tid + it*256;
                int c2  = idx & 31;
                int s   = idx >> 5;
                const TIN* g0 = in + (size_t)(k0 + c2*2    )*PIX + px0 + s*8;
                const TIN* g1 = in + (size_t)(k0 + c2*2 + 1)*PIX + px0 + s*8;
                unsigned short a8[8], b8[8];
                if constexpr (sizeof(TIN) == 2) {
                    *(uint4*)a8 = *(const uint4*)g0;
                    *(uint4*)b8 = *(const uint4*)g1;
                } else {
                    const float4 f0 = *(const float4*)g0;
                    const float4 f1 = *(const float4*)(g0+4);
                    const float4 f2 = *(const float4*)g1;
                    const float4 f3 = *(const float4*)(g1+4);
                    a8[0]=f2bf(f0.x); a8[1]=f2bf(f0.y); a8[2]=f2bf(f0.z); a8[3]=f2bf(f0.w);
                    a8[4]=f2bf(f1.x); a8[5]=f2bf(f1.y); a8[6]=f2bf(f1.z); a8[7]=f2bf(f1.w);
                    b8[0]=f2bf(f2.x); b8[1]=f2bf(f2.y); b8[2]=f2bf(f2.z); b8[3]=f2bf(f2.w);
                    b8[4]=f2bf(f3.x); b8[5]=f2bf(f3.y); b8[6]=f2bf(f3.z); b8[7]=f2bf(f3.w);
                }
                #pragma unroll
                for (int j=0;j<8;++j) {
                    unsigned pk = (unsigned)a8[j] | ((unsigned)b8[j] << 16);
                    *(unsigned*)&XL[(s*8+j)*CIP + c2*2] = pk;
                }
            }
        }
        __syncthreads();
        #pragma unroll
        for (int ks = 0; ks < 2; ++ks) {
            short8 a[4];
            #pragma unroll
            for (int mt=0; mt<4; ++mt) {
                int co = co0 + wco + mt*16 + l15;
                a[mt] = *(const short8*)(wq + (size_t)co*Cin + k0 + ks*32 + l4*8);
            }
            #pragma unroll
            for (int nt=0; nt<4; ++nt) {
                const short8 b = *(const short8*)&XL[(wpx + nt*16 + l15)*CIP + ks*32 + l4*8];
                #pragma unroll
                for (int mt=0; mt<4; ++mt)
                    acc[mt][nt] = __builtin_amdgcn_mfma_f32_16x16x32_bf16(a[mt], b, acc[mt][nt], 0, 0, 0);
            }
        }
    }
    #pragma unroll
    for (int mt=0; mt<4; ++mt) {
        #pragma unroll
        for (int r=0; r<4; ++r) {
            int co = co0 + wco + mt*16 + l4*4 + r;
            float bs = bias[co];
            #pragma unroll
            for (int nt=0; nt<4; ++nt) {
                int px = px0 + wpx + nt*16 + l15;
                float v = acc[mt][nt][r] + bs;
                if (DOGELU) v = gelu_f(v);
                size_t o = (size_t)co*PIX + px;
                if (DORES) v += res[o];
                if (OBF) outb[o] = f2bf(v);
                else     outf[o] = v;
            }
        }
    }
}

// ---------------- 3x3 dense conv 128->128 via bf16 MFMA + bias + skip ----------
// x-tile 32 (LDS 19.6KB -> 8 blocks/CU)
__global__ __launch_bounds__(256) void conv3x3_mfma_kernel(
    const unsigned short* __restrict__ inT,  // (B,PIX,128) bf16
    const unsigned short* __restrict__ wq,   // (128,9,128) bf16 [co][tap][ci]
    const float* __restrict__ bias, const float* __restrict__ skip,
    float* __restrict__ out)
{
    constexpr int CIP = 72;
    __shared__ unsigned short XL[4*34*CIP];  // 19,584 B
    const int x0 = blockIdx.x * 32;          // 0..5
    const int y0 = blockIdx.y * 2;           // 0..95
    const int bi = blockIdx.z;
    const int tid = threadIdx.x;
    const int lane = tid & 63, wid = tid >> 6;
    const int wco = (wid >> 1) * 64;
    const int wrow = wid & 1;
    const int l15 = lane & 15, l4 = lane >> 4;
    const unsigned short* inb = inT + (size_t)bi * PIX * 128;

    f32x4 acc[4][2];
    #pragma unroll
    for (int i=0;i<4;++i)
        #pragma unroll
        for (int j=0;j<2;++j) acc[i][j] = (f32x4){0.f,0.f,0.f,0.f};

    for (int ci0 = 0; ci0 < 128; ci0 += 64) {
        __syncthreads();
        #pragma unroll
        for (int it = 0; it < 5; ++it) {
            int idx = tid + it*256;          // 1088 tasks = 136 P x 8 q
            if (idx < 1088) {
                int P = idx >> 3;
                int q = idx & 7;
                int row = P / 34;
                int x = P - row*34;
                int gy = y0 - 1 + row, gx = x0 - 1 + x;
                uint4 v = {0u,0u,0u,0u};
                if ((unsigned)gy < (unsigned)HWD && (unsigned)gx < (unsigned)HWD)
                    v = *(const uint4*)&inb[((size_t)gy*HWD + gx)*128 + ci0 + q*8];
                *(uint4*)&XL[P*CIP + q*8] = v;
            }
        }
        __syncthreads();
        #pragma unroll
        for (int dy=0; dy<3; ++dy) {
            #pragma unroll
            for (int dx=0; dx<3; ++dx) {
                const int rl = wrow + dy;    // 0..3
                #pragma unroll
                for (int ks=0; ks<2; ++ks) {
                    short8 a[4];
                    #pragma unroll
                    for (int mt=0; mt<4; ++mt) {
                        int co = wco + mt*16 + l15;
                        a[mt] = *(const short8*)(wq + ((size_t)co*9 + dy*3+dx)*128 + ci0 + ks*32 + l4*8);
                    }
                    #pragma unroll
                    for (int nt=0; nt<2; ++nt) {
                        const int xl = nt*16 + l15 + dx;   // 0..33
                        const short8 b = *(const short8*)&XL[(rl*34 + xl)*CIP + ks*32 + l4*8];
                        #pragma unroll
                        for (int mt=0; mt<4; ++mt)
                            acc[mt][nt] = __builtin_amdgcn_mfma_f32_16x16x32_bf16(a[mt], b, acc[mt][nt], 0, 0, 0);
                    }
                }
            }
        }
    }
    const int gy = y0 + wrow;
    #pragma unroll
    for (int mt=0; mt<4; ++mt) {
        #pragma unroll
        for (int r=0; r<4; ++r) {
            int co = wco + mt*16 + l4*4 + r;
            float bs = bias[co];
            #pragma unroll
            for (int nt=0; nt<2; ++nt) {
                int gx = x0 + nt*16 + l15;
                size_t o = ((size_t)bi*CCH + co)*PIX + (size_t)gy*HWD + gx;
                out[o] = acc[mt][nt][r] + bs + skip[o];
            }
        }
    }
}

// ---------------- 13x13 dense conv 32->32 pad6 via bf16 MFMA + fused dyn dw3x3 -
// x-tile 32 (LDS 45KB -> 3 blocks/CU for latency hiding)
__global__ __launch_bounds__(256) void conv13_mfma_kernel(
    const unsigned short* __restrict__ YT,   // (B,PIX,32) bf16
    const unsigned short* __restrict__ wq,   // [169][32co][32ci] bf16
    const float* __restrict__ dk,            // [B*32][9]
    unsigned short* __restrict__ outL)       // (B,128,PIX) bf16, ch0..31
{
    __shared__ unsigned short XL[16*44*32];  // 45,056 B, swizzled
    const int x0 = blockIdx.x * 32;          // 0..5
    const int y0 = blockIdx.y * 4;           // 0..47
    const int bi = blockIdx.z;
    const int tid = threadIdx.x;
    const int lane = tid & 63, wr = tid >> 6;
    const int l15 = lane & 15, l4 = lane >> 4;
    const unsigned short* inT = YT + (size_t)bi * PIX * 32;

    #pragma unroll 1
    for (int it = 0; it < 11; ++it) {
        int idx = tid + it*256;              // 0..2815 = 704 P x 4 q
        int P = idx >> 2;
        int q = idx & 3;
        int row = P / 44;
        int x   = P - row*44;
        int gy = y0 - 6 + row, gx = x0 - 6 + x;
        uint4 v = {0u,0u,0u,0u};
        if ((unsigned)gy < (unsigned)HWD && (unsigned)gx < (unsigned)HWD)
            v = *(const uint4*)&inT[((size_t)gy*HWD + gx)*32 + q*8];
        *(uint4*)&XL[P*32 + ((q*8) ^ (((P>>1)&3)<<3))] = v;
    }
    __syncthreads();

    f32x4 acc[2][2];
    #pragma unroll
    for (int i=0;i<2;++i)
        #pragma unroll
        for (int j=0;j<2;++j) acc[i][j] = (f32x4){0.f,0.f,0.f,0.f};

    #pragma unroll 1
    for (int dy=0; dy<13; ++dy) {
        const unsigned short* wrow = wq + (size_t)dy*13*1024;
        #pragma unroll
        for (int dx=0; dx<13; ++dx) {
            const short8 a0 = *(const short8*)(wrow + dx*1024 + l15*32 + l4*8);
            const short8 a1 = *(const short8*)(wrow + dx*1024 + (16+l15)*32 + l4*8);
            #pragma unroll
            for (int nt=0; nt<2; ++nt) {
                const int P = (wr + dy)*44 + nt*16 + l15 + dx;
                const short8 b = *(const short8*)&XL[P*32 + ((l4*8) ^ (((P>>1)&3)<<3))];
                acc[0][nt] = __builtin_amdgcn_mfma_f32_16x16x32_bf16(a0, b, acc[0][nt], 0, 0, 0);
                acc[1][nt] = __builtin_amdgcn_mfma_f32_16x16x32_bf16(a1, b, acc[1][nt], 0, 0, 0);
            }
        }
    }
    const int gy = y0 + wr;
    #pragma unroll
    for (int mt=0; mt<2; ++mt) {
        #pragma unroll
        for (int r=0; r<4; ++r) {
            const int co = mt*16 + l4*4 + r;
            const float* dkk = dk + (bi*32 + co)*9;
            float k0=dkk[0],k1=dkk[1],k2=dkk[2],k3=dkk[3],k4=dkk[4],
                  k5=dkk[5],k6=dkk[6],k7=dkk[7],k8=dkk[8];
            #pragma unroll
            for (int nt=0; nt<2; ++nt) {
                const int px = nt*16 + l15;
                float dsum = 0.f;
                #pragma unroll
                for (int e=0; e<9; ++e) {
                    int ey = e/3, ex = e - ey*3;
                    int P = (wr+5+ey)*44 + px+5+ex;
                    float pv = bf2f(XL[P*32 + (co ^ (((P>>1)&3)<<3))]);
                    float kk = (e==0?k0:e==1?k1:e==2?k2:e==3?k3:e==4?k4:e==5?k5:e==6?k6:e==7?k7:k8);
                    dsum += pv * kk;
                }
                float v = acc[mt][nt][r] + dsum;
                outL[((size_t)bi*CCH + co)*PIX + (size_t)gy*HWD + x0 + px] = f2bf(v);
            }
        }
    }
}

// ---------------- depthwise 3x3 pad1 + bias, bf16 in/out, 8 px/thread ----------
__global__ __launch_bounds__(256) void dw3x3_bf_kernel(const unsigned short* __restrict__ in,
    const float* __restrict__ w, const float* __restrict__ b,
    unsigned short* __restrict__ out)
{
    int t = blockIdx.x*256 + threadIdx.x;     // nb*256*PIX/8 threads
    int pc = t / (PIX/8);
    int p8 = (t - pc*(PIX/8)) * 8;
    int c = pc & 255;
    int y = p8 / HWD, x0 = p8 - y*HWD;        // x0 multiple of 8 -> 16B aligned
    const unsigned short* ib = in + (size_t)pc * PIX;
    float wk[9];
    #pragma unroll
    for (int e=0;e<9;++e) wk[e] = w[c*9+e];
    float bc = b[c];
    float a[8];
    #pragma unroll
    for (int j=0;j<8;++j) a[j] = bc;
    float cen[8];
    #pragma unroll
    for (int ky=0;ky<3;++ky) {
        int yy = y + ky - 1;
        if ((unsigned)yy < (unsigned)HWD) {
            const unsigned short* row = ib + (size_t)yy*HWD;
            unsigned short e8[8];
            *(uint4*)e8 = *(const uint4*)&row[x0];
            float v[10];
            v[0] = (x0 > 0) ? bf2f(row[x0-1]) : 0.f;
            #pragma unroll
            for (int j=0;j<8;++j) v[j+1] = bf2f(e8[j]);
            v[9] = (x0 + 8 < HWD) ? bf2f(row[x0+8]) : 0.f;
            if (ky == 1) {
                #pragma unroll
                for (int j=0;j<8;++j) cen[j] = v[j+1];
            }
            const float w0 = wk[ky*3+0], w1 = wk[ky*3+1], w2 = wk[ky*3+2];
            #pragma unroll
            for (int j=0;j<8;++j)
                a[j] += v[j]*w0 + v[j+1]*w1 + v[j+2]*w2;
        } else if (ky == 1) {
            #pragma unroll
            for (int j=0;j<8;++j) cen[j] = 0.f;   // unreachable (y always valid)
        }
    }
    unsigned short r[8];
    #pragma unroll
    for (int j=0;j<8;++j) r[j] = f2bf(gelu_f(a[j]) + cen[j]);
    *(uint4*)(out + (size_t)pc*PIX + p8) = *(uint4*)r;
}

// ---------------- window attention via bf16 MFMA (win-major QKV) ---------------
__global__ __launch_bounds__(256) void attn_mfma_kernel(
    const unsigned short* __restrict__ qkv,  // (z, 384, 144*256) bf16 win-major
    const float* __restrict__ table,         // (4, 961) f32
    unsigned short* __restrict__ o)          // (z, 128, PIX) bf16 pixel-major
{
    __shared__ unsigned short KL[256*44];    // [k][c] pad44 (22,528 B)
    __shared__ unsigned short VL[32*264];    // [d][k] pad264 (16,896 B)
    __shared__ unsigned short PL[4*16*40];   // per-wave P k-tile (5,120 B)
    __shared__ float BT[961];
    __shared__ unsigned short OL[64*33];     // [q][d] pad33 (4,224 B)
    const int win = blockIdx.x, head = blockIdx.y;
    const int bi2 = blockIdx.z;
    const int wy = win/12, wx = win - wy*12;
    const int wb = win << 8;                 // win*256
    qkv += (size_t)bi2 * 384 * PIX;
    o   += (size_t)bi2 * CCH * PIX;
    const unsigned short* qb = qkv + (size_t)(head*32) * PIX;
    const unsigned short* kb = qkv + (size_t)(128 + head*32) * PIX;
    const unsigned short* vb = qkv + (size_t)(256 + head*32) * PIX;
    const int tid = threadIdx.x;

    // V: [d][k] direct uint4 copies (dense)
    #pragma unroll
    for (int it = 0; it < 4; ++it) {
        int idx = tid + it*256;
        int c = idx & 31, seg = idx >> 5;
        int k0 = seg*8;
        *(uint4*)&VL[c*264 + k0] = *(const uint4*)&vb[(size_t)c*PIX + wb + k0];
    }
    // K: uint4 global load (8 consecutive k for one c), scalar LDS transpose
    #pragma unroll
    for (int it = 0; it < 4; ++it) {
        int idx = tid + it*256;
        int c = idx & 31, seg = idx >> 5;
        int k0 = seg*8;
        unsigned short e[8];
        *(uint4*)e = *(const uint4*)&kb[(size_t)c*PIX + wb + k0];
        #pragma unroll
        for (int j=0;j<8;++j) KL[(k0+j)*44 + c] = e[j];
    }
    for (int i = tid; i < 961; i += 256) BT[i] = table[head*961 + i];
    __syncthreads();

    const int lane = tid & 63, w = tid >> 6;
    const int l15 = lane & 15, l4 = lane >> 4;
    const float scale = 0.17677669529663687f;   // 32^-0.5
    unsigned short* PLw = &PL[w*16*40];

    #pragma unroll 1
    for (int qc = 0; qc < 4; ++qc) {
        const int qi = qc*64 + w*16 + l15;
        const int iy = qi >> 4, ix = qi & 15;

        short8 qf;
        #pragma unroll
        for (int j=0;j<8;++j) qf[j] = (short)qb[(size_t)(l4*8+j)*PIX + wb + qi];

        f32x4 s[16];
        #pragma unroll
        for (int nt=0; nt<16; ++nt) {
            const short8 a = *(const short8*)&KL[(nt*16 + l15)*44 + l4*8];
            s[nt] = __builtin_amdgcn_mfma_f32_16x16x32_bf16(a, qf, (f32x4){0.f,0.f,0.f,0.f}, 0, 0, 0);
        }

        float m = -1e30f;
        #pragma unroll
        for (int nt=0; nt<16; ++nt) {
            #pragma unroll
            for (int r=0; r<4; ++r) {
                int k = nt*16 + l4*4 + r;
                float bv = BT[((k>>4) - iy + 15)*31 + ((k&15) - ix + 15)];
                float v = s[nt][r]*scale + bv;
                s[nt][r] = v;
                m = fmaxf(m, v);
            }
        }
        m = fmaxf(m, __shfl_xor(m, 16, 64));
        m = fmaxf(m, __shfl_xor(m, 32, 64));
        float l = 0.f;
        #pragma unroll
        for (int nt=0; nt<16; ++nt) {
            #pragma unroll
            for (int r=0; r<4; ++r) {
                float p = __expf(s[nt][r] - m);
                s[nt][r] = p;
                l += p;
            }
        }
        l += __shfl_xor(l, 16, 64);
        l += __shfl_xor(l, 32, 64);

        // PV: per 32-k tile, write P tile to per-wave LDS then consume
        f32x4 o0 = (f32x4){0.f,0.f,0.f,0.f}, o1 = (f32x4){0.f,0.f,0.f,0.f};
        #pragma unroll
        for (int kt=0; kt<8; ++kt) {
            #pragma unroll
            for (int h=0; h<2; ++h) {
                int nt = kt*2 + h;
                *(unsigned*)&PLw[l15*40 + h*16 + l4*4]     = pack2bf(s[nt][0], s[nt][1]);
                *(unsigned*)&PLw[l15*40 + h*16 + l4*4 + 2] = pack2bf(s[nt][2], s[nt][3]);
            }
            const short8 pa = *(const short8*)&PLw[l15*40 + l4*8];
            const short8 v0 = *(const short8*)&VL[l15*264 + kt*32 + l4*8];
            const short8 v1 = *(const short8*)&VL[(16+l15)*264 + kt*32 + l4*8];
            o0 = __builtin_amdgcn_mfma_f32_16x16x32_bf16(pa, v0, o0, 0, 0, 0);
            o1 = __builtin_amdgcn_mfma_f32_16x16x32_bf16(pa, v1, o1, 0, 0, 0);
        }

        #pragma unroll
        for (int r=0; r<4; ++r) {
            float lr = __shfl(l, l4*4 + r, 64);
            float inv = 1.f / lr;
            OL[(w*16 + l4*4 + r)*33 + l15]      = f2bf(o0[r]*inv);
            OL[(w*16 + l4*4 + r)*33 + 16 + l15] = f2bf(o1[r]*inv);
        }
        __syncthreads();

        // pixel-major output store (dense uint4)
        const int d = tid >> 3, seg = tid & 7;
        const int q0l = seg*8;
        const int qi0 = qc*64 + q0l;
        const int sp0 = ((wy<<4) + (qi0>>4))*HWD + (wx<<4) + (qi0 & 15);
        unsigned short tmp[8];
        #pragma unroll
        for (int j=0;j<8;++j) tmp[j] = OL[(q0l+j)*33 + d];
        *(uint4*)&o[(size_t)(head*32 + d)*PIX + sp0] = *(uint4*)tmp;
        __syncthreads();
    }
}

// ---------------- mean over spatial for channels 0..31 (bf16 in) ---------------
__global__ __launch_bounds__(256) void meanpool_kernel(const unsigned short* __restrict__ in,
    float* __restrict__ v)
{
    int bc = blockIdx.x;               // BB*32
    int bi = bc >> 5, c = bc & 31;
    const unsigned short* base = in + ((size_t)bi*CCH + c) * PIX;
    float s = 0.f;
    for (int i = threadIdx.x; i < PIX/4; i += 256) {
        const uint2 t4 = ((const uint2*)base)[i];
        s += bf2f((unsigned short)(t4.x & 0xffff)) + bf2f((unsigned short)(t4.x >> 16))
           + bf2f((unsigned short)(t4.y & 0xffff)) + bf2f((unsigned short)(t4.y >> 16));
    }
    #pragma unroll
    for (int off=32; off>0; off>>=1) s += __shfl_down(s, off, 64);
    __shared__ float red[4];
    if ((threadIdx.x & 63) == 0) red[threadIdx.x >> 6] = s;
    __syncthreads();
    if (threadIdx.x == 0) v[bc] = (red[0]+red[1]+red[2]+red[3]) * (1.f/PIX);
}

// ---------------- tiny MLP producing dynamic 3x3 kernels -----------------------
__global__ __launch_bounds__(256) void mlp_kernel(const float* __restrict__ v,
    const float* __restrict__ pw1, const float* __restrict__ pb1,
    const float* __restrict__ pw2, const float* __restrict__ pb2,
    float* __restrict__ dk)
{
    __shared__ float h[64];
    int tid = threadIdx.x;
    if (tid < 64) {
        int bi = tid >> 4, m = tid & 15;
        float s = pb1[m];
        for (int c=0;c<32;++c) s += v[bi*32+c]*pw1[m*32+c];
        h[tid] = gelu_f(s);
    }
    __syncthreads();
    for (int idx = tid; idx < BB*288; idx += 256) {
        int bi = idx / 288, j = idx - bi*288;
        float s = pb2[j];
        for (int m=0;m<16;++m) s += h[bi*16+m]*pw2[j*16+m];
        dk[idx] = s;
    }
}

// ---------------- merged weight prep (all casts + relayouts, one launch) -------
__global__ __launch_bounds__(256) void wprep_kernel(
    const float* __restrict__ proj_w1, const float* __restrict__ proj_w2,
    const float* __restrict__ qkv_w,   const float* __restrict__ attn_ow,
    const float* __restrict__ ffn_w1,  const float* __restrict__ ffn_w2,
    const float* __restrict__ aggr_w,  const float* __restrict__ co_w,
    const float* __restrict__ plk,     unsigned short* __restrict__ Q0)
{
    int idx = blockIdx.x*256 + threadIdx.x;
    if (idx < 32768) { Q0[idx] = f2bf(proj_w1[idx]); return; }
    idx -= 32768;
    if (idx < 32768) { Q0[32768 + idx] = f2bf(proj_w2[idx]); return; }
    idx -= 32768;
    if (idx < 49152) { Q0[65536 + idx] = f2bf(qkv_w[idx]); return; }
    idx -= 49152;
    if (idx < 16384) { Q0[114688 + idx] = f2bf(attn_ow[idx]); return; }
    idx -= 16384;
    if (idx < 65536) { Q0[131072 + idx] = f2bf(ffn_w1[idx]); return; }
    idx -= 65536;
    if (idx < 65536) { Q0[196608 + idx] = f2bf(ffn_w2[idx]); return; }
    idx -= 65536;
    if (idx < 32768) { Q0[262144 + idx] = f2bf(aggr_w[idx]); return; }
    idx -= 32768;
    if (idx < 147456) {          // co_w (128,128,3,3) -> [co][tap][ci]
        int co = idx / (128*9);
        int rem = idx - co*128*9;
        int ci = rem / 9;
        int tap = rem - ci*9;
        Q0[294912 + ((size_t)co*9 + tap)*128 + ci] = f2bf(co_w[idx]);
        return;
    }
    idx -= 147456;
    if (idx < 173056) {          // plk (32,32,13,13) -> [tap][co][ci]
        int co = idx / (32*169);
        int rem = idx - co*32*169;
        int ci = rem / 169;
        int tap = rem - ci*169;
        Q0[442368 + ((size_t)tap*32 + co)*32 + ci] = f2bf(plk[idx]);
    }
}

extern "C" void kernel_launch(void* const* d_in, const int* in_sizes, int n_in,
                              void* d_out, int out_size, void* d_ws, size_t ws_size,
                              hipStream_t stream) {
    (void)in_sizes; (void)n_in; (void)out_size;
    const float* x_in      = (const float*)d_in[0];
    const float* plk       = (const float*)d_in[1];
    const float* ln_proj_w = (const float*)d_in[2];
    const float* ln_proj_b = (const float*)d_in[3];
    const float* proj_w1   = (const float*)d_in[4];
    const float* proj_b1   = (const float*)d_in[5];
    const float* proj_dw   = (const float*)d_in[6];
    const float* proj_dwb  = (const float*)d_in[7];
    const float* proj_w2   = (const float*)d_in[8];
    const float* proj_b2   = (const float*)d_in[9];
    const float* ln_attn_w = (const float*)d_in[10];
    const float* ln_attn_b = (const float*)d_in[11];
    const float* qkv_w     = (const float*)d_in[12];
    const float* qkv_b     = (const float*)d_in[13];
    const float* attn_ow   = (const float*)d_in[14];
    const float* attn_ob   = (const float*)d_in[15];
    const float* rpe       = (const float*)d_in[16];
    const float* ffn_w1    = (const float*)d_in[17];
    const float* ffn_b1    = (const float*)d_in[18];
    const float* ffn_dw    = (const float*)d_in[19];
    const float* ffn_dwb   = (const float*)d_in[20];
    const float* ffn_w2    = (const float*)d_in[21];
    const float* ffn_b2    = (const float*)d_in[22];
    const float* pk_w1     = (const float*)d_in[23];
    const float* pk_b1     = (const float*)d_in[24];
    const float* pk_w2     = (const float*)d_in[25];
    const float* pk_b2     = (const float*)d_in[26];
    const float* aggr_w    = (const float*)d_in[27];
    const float* aggr_b    = (const float*)d_in[28];
    const float* ln_out_w  = (const float*)d_in[29];
    const float* ln_out_b  = (const float*)d_in[30];
    const float* co_w      = (const float*)d_in[31];
    const float* co_b      = (const float*)d_in[32];
    float* out = (float*)d_out;

    const size_t N1b = (size_t)CCH * PIX;          // elems per batch (128ch)
    const size_t RBsz = (size_t)BB * N1b;          // 18,874,368 fl
    const size_t LNYw = RBsz / 2;                  // bf16 (B,128,PIX) in fl-words
    const size_t YTw  = (size_t)BB*PIX*32/2;       // 2,359,296 fl
    const size_t QTOT = 615424;                    // bf16 weight elems (ushort)
    const size_t TAILw = 256 + 1152 + QTOT/2 + 64; // VB+DK+weights (fl)
    const size_t need_half = RBsz + LNYw + RBsz   + YTw + TAILw;
    const size_t need_full = RBsz + LNYw + 2*RBsz + YTw + TAILw;
    if (ws_size < need_half * sizeof(float)) return;   // diagnostic guard
    const bool full = ws_size >= need_full * sizeof(float);
    const size_t Ew = full ? 2*RBsz : RBsz;        // E-pool size in fl

    float* ws  = (float*)d_ws;
    float* RB  = ws;                               // fp32 residual x
    unsigned short* LNY  = (unsigned short*)(RB + RBsz);   // bf16
    unsigned short* EP   = (unsigned short*)(RB + RBsz + LNYw);    // E pool
    unsigned short* YT   = (unsigned short*)(RB + RBsz + LNYw + Ew);
    float* VB  = (float*)(RB + RBsz + LNYw + Ew + YTw);    // 256
    float* DK  = VB + 256;                                 // 1152
    unsigned short* Q0  = (unsigned short*)(DK + 1152);
    unsigned short* qPW1 = Q0;                 // 256*128
    unsigned short* qPW2 = qPW1 + 32768;       // 128*256
    unsigned short* qQKV = qPW2 + 32768;       // 384*128
    unsigned short* qAT  = qQKV + 49152;       // 128*128
    unsigned short* qF1  = qAT  + 16384;       // 2*256*128
    unsigned short* qF2  = qF1  + 65536;       // 2*128*256
    unsigned short* qAG  = qF2  + 65536;       // 2*128*128
    unsigned short* qW3  = qAG  + 32768;       // 128*9*128
    unsigned short* qW13 = qW3  + 147456;      // 169*32*32

    const int NZ = full ? BB : 2;              // batches per dispatch
    const int NH = full ? 1 : 2;               // halves
    unsigned short* E1 = EP;                   // NZ*256*PIX ushorts
    unsigned short* E2 = EP + (size_t)NZ*256*PIX;
    unsigned short* QKV = EP;                  // NZ*384*PIX ushorts (aliased)
    unsigned short* XT  = EP;                  // (B,PIX,128) (aliased)

    dim3 blk(256);

    // ---- merged weight prep (one launch) ----
    wprep_kernel<<<(615424+255)/256, blk, 0, stream>>>(
        proj_w1, proj_w2, qkv_w, attn_ow, ffn_w1, ffn_w2, aggr_w, co_w, plk, Q0);

    // x = conv_ffn(LN(x_in), proj)   [LN pixel-major -> TRANSIN conv]
    ln_t_kernel<<<576, blk, 0, stream>>>(x_in, ln_proj_w, ln_proj_b, LNY);
    for (int h=0; h<NH; ++h) {
        conv1x1_mfma_kernel<unsigned short,true,true,false,true,false><<<dim3(288,2,NZ), blk, 0, stream>>>(
            LNY + (size_t)h*NZ*N1b, qPW1, proj_b1, nullptr, E1, 128);
        dw3x3_bf_kernel<<<NZ*4608, blk, 0, stream>>>(E1, proj_dw, proj_dwb, E2);
        conv1x1_mfma_kernel<unsigned short,false,false,false,false,false><<<dim3(288,1,NZ), blk, 0, stream>>>(
            E2, qPW2, proj_b2, nullptr, RB + (size_t)h*NZ*N1b, 256);
    }

    // x = x + window_attention(LN(x))   [QKV in window-major pixel order]
    ln_t_kernel<<<576, blk, 0, stream>>>(RB, ln_attn_w, ln_attn_b, LNY);
    for (int h=0; h<NH; ++h) {
        conv1x1_mfma_kernel<unsigned short,true,false,false,true,true><<<dim3(288,3,NZ), blk, 0, stream>>>(
            LNY + (size_t)h*NZ*N1b, qQKV, qkv_b, nullptr, QKV, 128);
        attn_mfma_kernel<<<dim3(144,4,NZ), blk, 0, stream>>>(QKV, rpe, LNY + (size_t)h*NZ*N1b);
    }
    conv1x1_mfma_kernel<unsigned short,false,false,true,false,false><<<dim3(288,1,BB), blk, 0, stream>>>(
        LNY, qAT, attn_ob, RB, RB, 128);

    // x lives in RB; y lives in LNY channel-major
    for (int i=0;i<2;++i) {
        const float* fb1 = ffn_b1 + (size_t)i*256;
        const float* fdw = ffn_dw + (size_t)i*256*9;
        const float* fdb = ffn_dwb + (size_t)i*256;
        const float* fb2 = ffn_b2 + (size_t)i*128;
        const float* w1i = pk_w1 + (size_t)i*16*32;
        const float* b1i = pk_b1 + (size_t)i*16;
        const float* w2i = pk_w2 + (size_t)i*288*16;
        const float* b2i = pk_b2 + (size_t)i*288;
        const float* abi = aggr_b + (size_t)i*128;

        for (int h=0; h<NH; ++h) {
            conv1x1_mfma_kernel<float,false,true,false,true,false><<<dim3(288,2,NZ), blk, 0, stream>>>(
                RB + (size_t)h*NZ*N1b, qF1 + (size_t)i*32768, fb1, nullptr, E1, 128);
            dw3x3_bf_kernel<<<NZ*4608, blk, 0, stream>>>(E1, fdw, fdb, E2);
            conv1x1_mfma_kernel<unsigned short,false,false,false,true,false><<<dim3(288,1,NZ), blk, 0, stream>>>(
                E2, qF2 + (size_t)i*32768, fb2, nullptr, LNY + (size_t)h*NZ*N1b, 256);
        }
        t32_kernel<<<576, blk, 0, stream>>>(LNY, YT);
        meanpool_kernel<<<BB*32, blk, 0, stream>>>(LNY, VB);
        mlp_kernel<<<1, blk, 0, stream>>>(VB, w1i, b1i, w2i, b2i, DK);
        conv13_mfma_kernel<<<dim3(6,48,BB), blk, 0, stream>>>(YT, qW13, DK, LNY);
        conv1x1_mfma_kernel<unsigned short,false,false,true,false,false><<<dim3(288,1,BB), blk, 0, stream>>>(
            LNY, qAG + (size_t)i*16384, abi, RB, RB, 128);
    }

    // out = conv3x3(LN(x)) + bias + skip  [transposed LN output]
    ln_t_kernel<<<576, blk, 0, stream>>>(RB, ln_out_w, ln_out_b, XT);
    conv3x3_mfma_kernel<<<dim3(6,96,BB), blk, 0, stream>>>(XT, qW3, co_b, x_in, out);
}

// Round 22
// 1332.617 us; speedup vs baseline: 1.0477x; 1.0477x over previous
//
#include <hip/hip_runtime.h>
#include <cmath>

#define HWD 192
#define PIX (HWD*HWD)      // 36864
#define BB  4
#define CCH 128

using short8 = __attribute__((ext_vector_type(8))) short;
using f32x4  = __attribute__((ext_vector_type(4))) float;

__device__ __forceinline__ float gelu_f(float x) {
    return 0.5f * x * (1.0f + erff(x * 0.70710678118654752f));
}
__device__ __forceinline__ unsigned short f2bf(float f) {
    unsigned int u = __float_as_uint(f);
    u += 0x7fff + ((u >> 16) & 1);          // round-to-nearest-even
    return (unsigned short)(u >> 16);
}
__device__ __forceinline__ float bf2f(unsigned short s) {
    return __uint_as_float((unsigned int)s << 16);
}
__device__ __forceinline__ unsigned pack2bf(float a, float b) {
    return (unsigned)f2bf(a) | ((unsigned)f2bf(b) << 16);
}

// ---------------- LayerNorm: fp32 in, bf16 out TRANSPOSED (B,PIX,128) ----------
__global__ __launch_bounds__(256) void ln_t_kernel(const float* __restrict__ in,
        const float* __restrict__ w, const float* __restrict__ b,
        unsigned short* __restrict__ outT)
{
    int t = blockIdx.x * 256 + threadIdx.x;       // BB*PIX threads
    int bi = t / PIX;
    int p  = t - bi*PIX;
    const float* base = in + (size_t)bi * CCH * PIX + p;
    float v[CCH];
    float s = 0.f;
    #pragma unroll
    for (int c=0;c<CCH;++c) { v[c] = base[(size_t)c*PIX]; s += v[c]; }
    float m = s * (1.f/128.f);
    float q = 0.f;
    #pragma unroll
    for (int c=0;c<CCH;++c) { float d = v[c]-m; q += d*d; }
    float iv = rsqrtf(q*(1.f/128.f) + 1e-6f);
    unsigned short* ob = outT + ((size_t)bi * PIX + p) * 128;
    #pragma unroll
    for (int qq=0; qq<16; ++qq) {
        unsigned short e[8];
        #pragma unroll
        for (int j=0;j<8;++j) {
            int c = qq*8 + j;
            e[j] = f2bf((v[c]-m)*iv*w[c] + b[c]);
        }
        *(uint4*)&ob[qq*8] = *(uint4*)e;
    }
}

// ---------------- transpose y ch 0..31: (B,128,PIX) -> (B,PIX,32) --------------
__global__ __launch_bounds__(256) void t32_kernel(const unsigned short* __restrict__ in,
    unsigned short* __restrict__ outT)
{
    int t = blockIdx.x * 256 + threadIdx.x;       // BB*PIX threads
    int bi = t / PIX;
    int p  = t - bi*PIX;
    const unsigned short* base = in + (size_t)bi * CCH * PIX + p;
    unsigned short e[32];
    #pragma unroll
    for (int c=0;c<32;++c) e[c] = base[(size_t)c*PIX];
    unsigned short* ob = outT + ((size_t)bi * PIX + p) * 32;
    #pragma unroll
    for (int q=0;q<4;++q) *(uint4*)&ob[q*8] = *(uint4*)&e[q*8];
}

// ---------------- 1x1 conv via bf16 MFMA ---------------------------------------
// WINPERM (with TRANSIN): stage pixel perm(wk) so output pixel axis is
// window-major (win*256 + k). 1x1 conv is pixel-permutation invariant.
template<typename TIN, bool TRANSIN, bool DOGELU, bool DORES, bool OBF, bool WINPERM>
__global__ __launch_bounds__(256) void conv1x1_mfma_kernel(
    const TIN* __restrict__ in,
    const unsigned short* __restrict__ wq,   // (Cout, Cin) bf16
    const float* __restrict__ bias,
    const float* __restrict__ res,           // (z, Cout, PIX) fp32 or null
    void* __restrict__ outv,                 // (z, Cout, PIX)
    int Cin)
{
    constexpr int CIP = 72;
    __shared__ unsigned short XL[128*CIP];   // 18,432 B
    const int Cout = gridDim.y * 128;
    const int px0 = blockIdx.x * 128;
    const int co0 = blockIdx.y * 128;
    const size_t bi = blockIdx.z;
    in  += bi * (size_t)Cin * PIX;
    if (DORES) res += bi * (size_t)Cout * PIX;
    float* outf = (float*)outv + bi * (size_t)Cout * PIX;
    unsigned short* outb = (unsigned short*)outv + bi * (size_t)Cout * PIX;
    const int tid = threadIdx.x;
    const int lane = tid & 63, wid = tid >> 6;
    const int wco = (wid >> 1) * 64;
    const int wpx = (wid & 1) * 64;
    const int l15 = lane & 15, l4 = lane >> 4;

    f32x4 acc[4][4];
    #pragma unroll
    for (int i=0;i<4;++i)
        #pragma unroll
        for (int j=0;j<4;++j) acc[i][j] = (f32x4){0.f,0.f,0.f,0.f};

    for (int k0 = 0; k0 < Cin; k0 += 64) {
        __syncthreads();
        if constexpr (TRANSIN) {
            #pragma unroll
            for (int it = 0; it < 4; ++it) {
                int idx = tid + it*256;
                int q = idx & 7, pxl = idx >> 3;
                int src;
                if constexpr (WINPERM) {
                    int wk = px0 + pxl;
                    int win = wk >> 8, k = wk & 255;
                    int wy = win / 12, wxw = win - wy*12;
                    src = ((wy<<4) + (k>>4))*HWD + (wxw<<4) + (k&15);
                } else {
                    src = px0 + pxl;
                }
                const uint4 v = *(const uint4*)((const unsigned short*)in
                                + ((size_t)src)*128 + k0 + q*8);
                *(uint4*)&XL[pxl*CIP + q*8] = v;
            }
        } else {
            #pragma unroll
            for (int it = 0; it < 2; ++it) {
                int idx = tid + it*256;
                int c2  = idx & 31;
                int s   = idx >> 5;
                const TIN* g0 = in + (size_t)(k0 + c2*2    )*PIX + px0 + s*8;
                const TIN* g1 = in + (size_t)(k0 + c2*2 + 1)*PIX + px0 + s*8;
                unsigned short a8[8], b8[8];
                if constexpr (sizeof(TIN) == 2) {
                    *(uint4*)a8 = *(const uint4*)g0;
                    *(uint4*)b8 = *(const uint4*)g1;
                } else {
                    const float4 f0 = *(const float4*)g0;
                    const float4 f1 = *(const float4*)(g0+4);
                    const float4 f2 = *(const float4*)g1;
                    const float4 f3 = *(const float4*)(g1+4);
                    a8[0]=f2bf(f0.x); a8[1]=f2bf(f0.y); a8[2]=f2bf(f0.z); a8[3]=f2bf(f0.w);
                    a8[4]=f2bf(f1.x); a8[5]=f2bf(f1.y); a8[6]=f2bf(f1.z); a8[7]=f2bf(f1.w);
                    b8[0]=f2bf(f2.x); b8[1]=f2bf(f2.y); b8[2]=f2bf(f2.z); b8[3]=f2bf(f2.w);
                    b8[4]=f2bf(f3.x); b8[5]=f2bf(f3.y); b8[6]=f2bf(f3.z); b8[7]=f2bf(f3.w);
                }
                #pragma unroll
                for (int j=0;j<8;++j) {
                    unsigned pk = (unsigned)a8[j] | ((unsigned)b8[j] << 16);
                    *(unsigned*)&XL[(s*8+j)*CIP + c2*2] = pk;
                }
            }
        }
        __syncthreads();
        #pragma unroll
        for (int ks = 0; ks < 2; ++ks) {
            short8 a[4];
            #pragma unroll
            for (int mt=0; mt<4; ++mt) {
                int co = co0 + wco + mt*16 + l15;
                a[mt] = *(const short8*)(wq + (size_t)co*Cin + k0 + ks*32 + l4*8);
            }
            #pragma unroll
            for (int nt=0; nt<4; ++nt) {
                const short8 b = *(const short8*)&XL[(wpx + nt*16 + l15)*CIP + ks*32 + l4*8];
                #pragma unroll
                for (int mt=0; mt<4; ++mt)
                    acc[mt][nt] = __builtin_amdgcn_mfma_f32_16x16x32_bf16(a[mt], b, acc[mt][nt], 0, 0, 0);
            }
        }
    }
    #pragma unroll
    for (int mt=0; mt<4; ++mt) {
        #pragma unroll
        for (int r=0; r<4; ++r) {
            int co = co0 + wco + mt*16 + l4*4 + r;
            float bs = bias[co];
            #pragma unroll
            for (int nt=0; nt<4; ++nt) {
                int px = px0 + wpx + nt*16 + l15;
                float v = acc[mt][nt][r] + bs;
                if (DOGELU) v = gelu_f(v);
                size_t o = (size_t)co*PIX + px;
                if (DORES) v += res[o];
                if (OBF) outb[o] = f2bf(v);
                else     outf[o] = v;
            }
        }
    }
}

// ---------------- 3x3 dense conv 128->128 via bf16 MFMA + bias + skip ----------
// y-tile 1, x-tile 64: LDS 28.5KB -> 5 blocks/CU; weight reuse ratio preserved
__global__ __launch_bounds__(256) void conv3x3_mfma_kernel(
    const unsigned short* __restrict__ inT,  // (B,PIX,128) bf16
    const unsigned short* __restrict__ wq,   // (128,9,128) bf16 [co][tap][ci]
    const float* __restrict__ bias, const float* __restrict__ skip,
    float* __restrict__ out)
{
    constexpr int CIP = 72;
    __shared__ unsigned short XL[3*66*CIP];  // 28,512 B
    const int x0 = blockIdx.x * 64;          // 0..2
    const int y0 = blockIdx.y;               // 0..191
    const int bi = blockIdx.z;
    const int tid = threadIdx.x;
    const int lane = tid & 63, w = tid >> 6; // wave owns co w*32..w*32+31
    const int l15 = lane & 15, l4 = lane >> 4;
    const unsigned short* inb = inT + (size_t)bi * PIX * 128;

    f32x4 acc[2][4];
    #pragma unroll
    for (int i=0;i<2;++i)
        #pragma unroll
        for (int j=0;j<4;++j) acc[i][j] = (f32x4){0.f,0.f,0.f,0.f};

    for (int ci0 = 0; ci0 < 128; ci0 += 64) {
        __syncthreads();
        #pragma unroll
        for (int it = 0; it < 7; ++it) {
            int idx = tid + it*256;          // 1584 tasks = 198 P x 8 q
            if (idx < 1584) {
                int P = idx >> 3;
                int q = idx & 7;
                int row = P / 66;
                int x = P - row*66;
                int gy = y0 - 1 + row, gx = x0 - 1 + x;
                uint4 v = {0u,0u,0u,0u};
                if ((unsigned)gy < (unsigned)HWD && (unsigned)gx < (unsigned)HWD)
                    v = *(const uint4*)&inb[((size_t)gy*HWD + gx)*128 + ci0 + q*8];
                *(uint4*)&XL[P*CIP + q*8] = v;
            }
        }
        __syncthreads();
        #pragma unroll
        for (int dy=0; dy<3; ++dy) {
            #pragma unroll
            for (int dx=0; dx<3; ++dx) {
                #pragma unroll
                for (int ks=0; ks<2; ++ks) {
                    short8 a[2];
                    #pragma unroll
                    for (int mt=0; mt<2; ++mt) {
                        int co = w*32 + mt*16 + l15;
                        a[mt] = *(const short8*)(wq + ((size_t)co*9 + dy*3+dx)*128 + ci0 + ks*32 + l4*8);
                    }
                    #pragma unroll
                    for (int nt=0; nt<4; ++nt) {
                        const int xl = nt*16 + l15 + dx;   // 0..65
                        const short8 b = *(const short8*)&XL[(dy*66 + xl)*CIP + ks*32 + l4*8];
                        #pragma unroll
                        for (int mt=0; mt<2; ++mt)
                            acc[mt][nt] = __builtin_amdgcn_mfma_f32_16x16x32_bf16(a[mt], b, acc[mt][nt], 0, 0, 0);
                    }
                }
            }
        }
    }
    #pragma unroll
    for (int mt=0; mt<2; ++mt) {
        #pragma unroll
        for (int r=0; r<4; ++r) {
            int co = w*32 + mt*16 + l4*4 + r;
            float bs = bias[co];
            #pragma unroll
            for (int nt=0; nt<4; ++nt) {
                int gx = x0 + nt*16 + l15;
                size_t o = ((size_t)bi*CCH + co)*PIX + (size_t)y0*HWD + gx;
                out[o] = acc[mt][nt][r] + bs + skip[o];
            }
        }
    }
}

// ---------------- 13x13 dense conv 32->32 pad6 via bf16 MFMA + fused dyn dw3x3 -
// x-tile 32 (LDS 45KB -> 3 blocks/CU for latency hiding)
__global__ __launch_bounds__(256) void conv13_mfma_kernel(
    const unsigned short* __restrict__ YT,   // (B,PIX,32) bf16
    const unsigned short* __restrict__ wq,   // [169][32co][32ci] bf16
    const float* __restrict__ dk,            // [B*32][9]
    unsigned short* __restrict__ outL)       // (B,128,PIX) bf16, ch0..31
{
    __shared__ unsigned short XL[16*44*32];  // 45,056 B, swizzled
    const int x0 = blockIdx.x * 32;          // 0..5
    const int y0 = blockIdx.y * 4;           // 0..47
    const int bi = blockIdx.z;
    const int tid = threadIdx.x;
    const int lane = tid & 63, wr = tid >> 6;
    const int l15 = lane & 15, l4 = lane >> 4;
    const unsigned short* inT = YT + (size_t)bi * PIX * 32;

    #pragma unroll 1
    for (int it = 0; it < 11; ++it) {
        int idx = tid + it*256;              // 0..2815 = 704 P x 4 q
        int P = idx >> 2;
        int q = idx & 3;
        int row = P / 44;
        int x   = P - row*44;
        int gy = y0 - 6 + row, gx = x0 - 6 + x;
        uint4 v = {0u,0u,0u,0u};
        if ((unsigned)gy < (unsigned)HWD && (unsigned)gx < (unsigned)HWD)
            v = *(const uint4*)&inT[((size_t)gy*HWD + gx)*32 + q*8];
        *(uint4*)&XL[P*32 + ((q*8) ^ (((P>>1)&3)<<3))] = v;
    }
    __syncthreads();

    f32x4 acc[2][2];
    #pragma unroll
    for (int i=0;i<2;++i)
        #pragma unroll
        for (int j=0;j<2;++j) acc[i][j] = (f32x4){0.f,0.f,0.f,0.f};

    #pragma unroll 1
    for (int dy=0; dy<13; ++dy) {
        const unsigned short* wrow = wq + (size_t)dy*13*1024;
        #pragma unroll
        for (int dx=0; dx<13; ++dx) {
            const short8 a0 = *(const short8*)(wrow + dx*1024 + l15*32 + l4*8);
            const short8 a1 = *(const short8*)(wrow + dx*1024 + (16+l15)*32 + l4*8);
            #pragma unroll
            for (int nt=0; nt<2; ++nt) {
                const int P = (wr + dy)*44 + nt*16 + l15 + dx;
                const short8 b = *(const short8*)&XL[P*32 + ((l4*8) ^ (((P>>1)&3)<<3))];
                acc[0][nt] = __builtin_amdgcn_mfma_f32_16x16x32_bf16(a0, b, acc[0][nt], 0, 0, 0);
                acc[1][nt] = __builtin_amdgcn_mfma_f32_16x16x32_bf16(a1, b, acc[1][nt], 0, 0, 0);
            }
        }
    }
    const int gy = y0 + wr;
    #pragma unroll
    for (int mt=0; mt<2; ++mt) {
        #pragma unroll
        for (int r=0; r<4; ++r) {
            const int co = mt*16 + l4*4 + r;
            const float* dkk = dk + (bi*32 + co)*9;
            float k0=dkk[0],k1=dkk[1],k2=dkk[2],k3=dkk[3],k4=dkk[4],
                  k5=dkk[5],k6=dkk[6],k7=dkk[7],k8=dkk[8];
            #pragma unroll
            for (int nt=0; nt<2; ++nt) {
                const int px = nt*16 + l15;
                float dsum = 0.f;
                #pragma unroll
                for (int e=0; e<9; ++e) {
                    int ey = e/3, ex = e - ey*3;
                    int P = (wr+5+ey)*44 + px+5+ex;
                    float pv = bf2f(XL[P*32 + (co ^ (((P>>1)&3)<<3))]);
                    float kk = (e==0?k0:e==1?k1:e==2?k2:e==3?k3:e==4?k4:e==5?k5:e==6?k6:e==7?k7:k8);
                    dsum += pv * kk;
                }
                float v = acc[mt][nt][r] + dsum;
                outL[((size_t)bi*CCH + co)*PIX + (size_t)gy*HWD + x0 + px] = f2bf(v);
            }
        }
    }
}

// ---------------- depthwise 3x3 pad1 + bias, bf16 in/out, 8 px/thread ----------
__global__ __launch_bounds__(256) void dw3x3_bf_kernel(const unsigned short* __restrict__ in,
    const float* __restrict__ w, const float* __restrict__ b,
    unsigned short* __restrict__ out)
{
    int t = blockIdx.x*256 + threadIdx.x;     // nb*256*PIX/8 threads
    int pc = t / (PIX/8);
    int p8 = (t - pc*(PIX/8)) * 8;
    int c = pc & 255;
    int y = p8 / HWD, x0 = p8 - y*HWD;        // x0 multiple of 8 -> 16B aligned
    const unsigned short* ib = in + (size_t)pc * PIX;
    float wk[9];
    #pragma unroll
    for (int e=0;e<9;++e) wk[e] = w[c*9+e];
    float bc = b[c];
    float a[8];
    #pragma unroll
    for (int j=0;j<8;++j) a[j] = bc;
    float cen[8];
    #pragma unroll
    for (int ky=0;ky<3;++ky) {
        int yy = y + ky - 1;
        if ((unsigned)yy < (unsigned)HWD) {
            const unsigned short* row = ib + (size_t)yy*HWD;
            unsigned short e8[8];
            *(uint4*)e8 = *(const uint4*)&row[x0];
            float v[10];
            v[0] = (x0 > 0) ? bf2f(row[x0-1]) : 0.f;
            #pragma unroll
            for (int j=0;j<8;++j) v[j+1] = bf2f(e8[j]);
            v[9] = (x0 + 8 < HWD) ? bf2f(row[x0+8]) : 0.f;
            if (ky == 1) {
                #pragma unroll
                for (int j=0;j<8;++j) cen[j] = v[j+1];
            }
            const float w0 = wk[ky*3+0], w1 = wk[ky*3+1], w2 = wk[ky*3+2];
            #pragma unroll
            for (int j=0;j<8;++j)
                a[j] += v[j]*w0 + v[j+1]*w1 + v[j+2]*w2;
        } else if (ky == 1) {
            #pragma unroll
            for (int j=0;j<8;++j) cen[j] = 0.f;   // unreachable (y always valid)
        }
    }
    unsigned short r[8];
    #pragma unroll
    for (int j=0;j<8;++j) r[j] = f2bf(gelu_f(a[j]) + cen[j]);
    *(uint4*)(out + (size_t)pc*PIX + p8) = *(uint4*)r;
}

// ---------------- window attention via bf16 MFMA (win-major QKV) ---------------
__global__ __launch_bounds__(256) void attn_mfma_kernel(
    const unsigned short* __restrict__ qkv,  // (z, 384, 144*256) bf16 win-major
    const float* __restrict__ table,         // (4, 961) f32
    unsigned short* __restrict__ o)          // (z, 128, PIX) bf16 pixel-major
{
    __shared__ unsigned short KL[256*44];    // [k][c] pad44 (22,528 B)
    __shared__ unsigned short VL[32*264];    // [d][k] pad264 (16,896 B)
    __shared__ unsigned short PL[4*16*40];   // per-wave P k-tile (5,120 B)
    __shared__ float BT[961];
    __shared__ unsigned short OL[64*33];     // [q][d] pad33 (4,224 B)
    const int win = blockIdx.x, head = blockIdx.y;
    const int bi2 = blockIdx.z;
    const int wy = win/12, wx = win - wy*12;
    const int wb = win << 8;                 // win*256
    qkv += (size_t)bi2 * 384 * PIX;
    o   += (size_t)bi2 * CCH * PIX;
    const unsigned short* qb = qkv + (size_t)(head*32) * PIX;
    const unsigned short* kb = qkv + (size_t)(128 + head*32) * PIX;
    const unsigned short* vb = qkv + (size_t)(256 + head*32) * PIX;
    const int tid = threadIdx.x;

    // V: [d][k] direct uint4 copies (dense)
    #pragma unroll
    for (int it = 0; it < 4; ++it) {
        int idx = tid + it*256;
        int c = idx & 31, seg = idx >> 5;
        int k0 = seg*8;
        *(uint4*)&VL[c*264 + k0] = *(const uint4*)&vb[(size_t)c*PIX + wb + k0];
    }
    // K: uint4 global load (8 consecutive k for one c), scalar LDS transpose
    #pragma unroll
    for (int it = 0; it < 4; ++it) {
        int idx = tid + it*256;
        int c = idx & 31, seg = idx >> 5;
        int k0 = seg*8;
        unsigned short e[8];
        *(uint4*)e = *(const uint4*)&kb[(size_t)c*PIX + wb + k0];
        #pragma unroll
        for (int j=0;j<8;++j) KL[(k0+j)*44 + c] = e[j];
    }
    for (int i = tid; i < 961; i += 256) BT[i] = table[head*961 + i];
    __syncthreads();

    const int lane = tid & 63, w = tid >> 6;
    const int l15 = lane & 15, l4 = lane >> 4;
    const float scale = 0.17677669529663687f;   // 32^-0.5
    unsigned short* PLw = &PL[w*16*40];

    #pragma unroll 1
    for (int qc = 0; qc < 4; ++qc) {
        const int qi = qc*64 + w*16 + l15;
        const int iy = qi >> 4, ix = qi & 15;

        short8 qf;
        #pragma unroll
        for (int j=0;j<8;++j) qf[j] = (short)qb[(size_t)(l4*8+j)*PIX + wb + qi];

        f32x4 s[16];
        #pragma unroll
        for (int nt=0; nt<16; ++nt) {
            const short8 a = *(const short8*)&KL[(nt*16 + l15)*44 + l4*8];
            s[nt] = __builtin_amdgcn_mfma_f32_16x16x32_bf16(a, qf, (f32x4){0.f,0.f,0.f,0.f}, 0, 0, 0);
        }

        float m = -1e30f;
        #pragma unroll
        for (int nt=0; nt<16; ++nt) {
            #pragma unroll
            for (int r=0; r<4; ++r) {
                int k = nt*16 + l4*4 + r;
                float bv = BT[((k>>4) - iy + 15)*31 + ((k&15) - ix + 15)];
                float v = s[nt][r]*scale + bv;
                s[nt][r] = v;
                m = fmaxf(m, v);
            }
        }
        m = fmaxf(m, __shfl_xor(m, 16, 64));
        m = fmaxf(m, __shfl_xor(m, 32, 64));
        float l = 0.f;
        #pragma unroll
        for (int nt=0; nt<16; ++nt) {
            #pragma unroll
            for (int r=0; r<4; ++r) {
                float p = __expf(s[nt][r] - m);
                s[nt][r] = p;
                l += p;
            }
        }
        l += __shfl_xor(l, 16, 64);
        l += __shfl_xor(l, 32, 64);

        // PV: per 32-k tile, write P tile to per-wave LDS then consume
        f32x4 o0 = (f32x4){0.f,0.f,0.f,0.f}, o1 = (f32x4){0.f,0.f,0.f,0.f};
        #pragma unroll
        for (int kt=0; kt<8; ++kt) {
            #pragma unroll
            for (int h=0; h<2; ++h) {
                int nt = kt*2 + h;
                *(unsigned*)&PLw[l15*40 + h*16 + l4*4]     = pack2bf(s[nt][0], s[nt][1]);
                *(unsigned*)&PLw[l15*40 + h*16 + l4*4 + 2] = pack2bf(s[nt][2], s[nt][3]);
            }
            const short8 pa = *(const short8*)&PLw[l15*40 + l4*8];
            const short8 v0 = *(const short8*)&VL[l15*264 + kt*32 + l4*8];
            const short8 v1 = *(const short8*)&VL[(16+l15)*264 + kt*32 + l4*8];
            o0 = __builtin_amdgcn_mfma_f32_16x16x32_bf16(pa, v0, o0, 0, 0, 0);
            o1 = __builtin_amdgcn_mfma_f32_16x16x32_bf16(pa, v1, o1, 0, 0, 0);
        }

        #pragma unroll
        for (int r=0; r<4; ++r) {
            float lr = __shfl(l, l4*4 + r, 64);
            float inv = 1.f / lr;
            OL[(w*16 + l4*4 + r)*33 + l15]      = f2bf(o0[r]*inv);
            OL[(w*16 + l4*4 + r)*33 + 16 + l15] = f2bf(o1[r]*inv);
        }
        __syncthreads();

        // pixel-major output store (dense uint4)
        const int d = tid >> 3, seg = tid & 7;
        const int q0l = seg*8;
        const int qi0 = qc*64 + q0l;
        const int sp0 = ((wy<<4) + (qi0>>4))*HWD + (wx<<4) + (qi0 & 15);
        unsigned short tmp[8];
        #pragma unroll
        for (int j=0;j<8;++j) tmp[j] = OL[(q0l+j)*33 + d];
        *(uint4*)&o[(size_t)(head*32 + d)*PIX + sp0] = *(uint4*)tmp;
        __syncthreads();
    }
}

// ---------------- mean over spatial for channels 0..31 (bf16 in) ---------------
__global__ __launch_bounds__(256) void meanpool_kernel(const unsigned short* __restrict__ in,
    float* __restrict__ v)
{
    int bc = blockIdx.x;               // BB*32
    int bi = bc >> 5, c = bc & 31;
    const unsigned short* base = in + ((size_t)bi*CCH + c) * PIX;
    float s = 0.f;
    for (int i = threadIdx.x; i < PIX/4; i += 256) {
        const uint2 t4 = ((const uint2*)base)[i];
        s += bf2f((unsigned short)(t4.x & 0xffff)) + bf2f((unsigned short)(t4.x >> 16))
           + bf2f((unsigned short)(t4.y & 0xffff)) + bf2f((unsigned short)(t4.y >> 16));
    }
    #pragma unroll
    for (int off=32; off>0; off>>=1) s += __shfl_down(s, off, 64);
    __shared__ float red[4];
    if ((threadIdx.x & 63) == 0) red[threadIdx.x >> 6] = s;
    __syncthreads();
    if (threadIdx.x == 0) v[bc] = (red[0]+red[1]+red[2]+red[3]) * (1.f/PIX);
}

// ---------------- tiny MLP producing dynamic 3x3 kernels -----------------------
__global__ __launch_bounds__(256) void mlp_kernel(const float* __restrict__ v,
    const float* __restrict__ pw1, const float* __restrict__ pb1,
    const float* __restrict__ pw2, const float* __restrict__ pb2,
    float* __restrict__ dk)
{
    __shared__ float h[64];
    int tid = threadIdx.x;
    if (tid < 64) {
        int bi = tid >> 4, m = tid & 15;
        float s = pb1[m];
        for (int c=0;c<32;++c) s += v[bi*32+c]*pw1[m*32+c];
        h[tid] = gelu_f(s);
    }
    __syncthreads();
    for (int idx = tid; idx < BB*288; idx += 256) {
        int bi = idx / 288, j = idx - bi*288;
        float s = pb2[j];
        for (int m=0;m<16;++m) s += h[bi*16+m]*pw2[j*16+m];
        dk[idx] = s;
    }
}

// ---------------- merged weight prep (all casts + relayouts, one launch) -------
__global__ __launch_bounds__(256) void wprep_kernel(
    const float* __restrict__ proj_w1, const float* __restrict__ proj_w2,
    const float* __restrict__ qkv_w,   const float* __restrict__ attn_ow,
    const float* __restrict__ ffn_w1,  const float* __restrict__ ffn_w2,
    const float* __restrict__ aggr_w,  const float* __restrict__ co_w,
    const float* __restrict__ plk,     unsigned short* __restrict__ Q0)
{
    int idx = blockIdx.x*256 + threadIdx.x;
    if (idx < 32768) { Q0[idx] = f2bf(proj_w1[idx]); return; }
    idx -= 32768;
    if (idx < 32768) { Q0[32768 + idx] = f2bf(proj_w2[idx]); return; }
    idx -= 32768;
    if (idx < 49152) { Q0[65536 + idx] = f2bf(qkv_w[idx]); return; }
    idx -= 49152;
    if (idx < 16384) { Q0[114688 + idx] = f2bf(attn_ow[idx]); return; }
    idx -= 16384;
    if (idx < 65536) { Q0[131072 + idx] = f2bf(ffn_w1[idx]); return; }
    idx -= 65536;
    if (idx < 65536) { Q0[196608 + idx] = f2bf(ffn_w2[idx]); return; }
    idx -= 65536;
    if (idx < 32768) { Q0[262144 + idx] = f2bf(aggr_w[idx]); return; }
    idx -= 32768;
    if (idx < 147456) {          // co_w (128,128,3,3) -> [co][tap][ci]
        int co = idx / (128*9);
        int rem = idx - co*128*9;
        int ci = rem / 9;
        int tap = rem - ci*9;
        Q0[294912 + ((size_t)co*9 + tap)*128 + ci] = f2bf(co_w[idx]);
        return;
    }
    idx -= 147456;
    if (idx < 173056) {          // plk (32,32,13,13) -> [tap][co][ci]
        int co = idx / (32*169);
        int rem = idx - co*32*169;
        int ci = rem / 169;
        int tap = rem - ci*169;
        Q0[442368 + ((size_t)tap*32 + co)*32 + ci] = f2bf(plk[idx]);
    }
}

extern "C" void kernel_launch(void* const* d_in, const int* in_sizes, int n_in,
                              void* d_out, int out_size, void* d_ws, size_t ws_size,
                              hipStream_t stream) {
    (void)in_sizes; (void)n_in; (void)out_size;
    const float* x_in      = (const float*)d_in[0];
    const float* plk       = (const float*)d_in[1];
    const float* ln_proj_w = (const float*)d_in[2];
    const float* ln_proj_b = (const float*)d_in[3];
    const float* proj_w1   = (const float*)d_in[4];
    const float* proj_b1   = (const float*)d_in[5];
    const float* proj_dw   = (const float*)d_in[6];
    const float* proj_dwb  = (const float*)d_in[7];
    const float* proj_w2   = (const float*)d_in[8];
    const float* proj_b2   = (const float*)d_in[9];
    const float* ln_attn_w = (const float*)d_in[10];
    const float* ln_attn_b = (const float*)d_in[11];
    const float* qkv_w     = (const float*)d_in[12];
    const float* qkv_b     = (const float*)d_in[13];
    const float* attn_ow   = (const float*)d_in[14];
    const float* attn_ob   = (const float*)d_in[15];
    const float* rpe       = (const float*)d_in[16];
    const float* ffn_w1    = (const float*)d_in[17];
    const float* ffn_b1    = (const float*)d_in[18];
    const float* ffn_dw    = (const float*)d_in[19];
    const float* ffn_dwb   = (const float*)d_in[20];
    const float* ffn_w2    = (const float*)d_in[21];
    const float* ffn_b2    = (const float*)d_in[22];
    const float* pk_w1     = (const float*)d_in[23];
    const float* pk_b1     = (const float*)d_in[24];
    const float* pk_w2     = (const float*)d_in[25];
    const float* pk_b2     = (const float*)d_in[26];
    const float* aggr_w    = (const float*)d_in[27];
    const float* aggr_b    = (const float*)d_in[28];
    const float* ln_out_w  = (const float*)d_in[29];
    const float* ln_out_b  = (const float*)d_in[30];
    const float* co_w      = (const float*)d_in[31];
    const float* co_b      = (const float*)d_in[32];
    float* out = (float*)d_out;

    const size_t N1b = (size_t)CCH * PIX;          // elems per batch (128ch)
    const size_t RBsz = (size_t)BB * N1b;          // 18,874,368 fl
    const size_t LNYw = RBsz / 2;                  // bf16 (B,128,PIX) in fl-words
    const size_t YTw  = (size_t)BB*PIX*32/2;       // 2,359,296 fl
    const size_t QTOT = 615424;                    // bf16 weight elems (ushort)
    const size_t TAILw = 256 + 1152 + QTOT/2 + 64; // VB+DK+weights (fl)
    const size_t need_half = RBsz + LNYw + RBsz   + YTw + TAILw;
    const size_t need_full = RBsz + LNYw + 2*RBsz + YTw + TAILw;
    if (ws_size < need_half * sizeof(float)) return;   // diagnostic guard
    const bool full = ws_size >= need_full * sizeof(float);
    const size_t Ew = full ? 2*RBsz : RBsz;        // E-pool size in fl

    float* ws  = (float*)d_ws;
    float* RB  = ws;                               // fp32 residual x
    unsigned short* LNY  = (unsigned short*)(RB + RBsz);   // bf16
    unsigned short* EP   = (unsigned short*)(RB + RBsz + LNYw);    // E pool
    unsigned short* YT   = (unsigned short*)(RB + RBsz + LNYw + Ew);
    float* VB  = (float*)(RB + RBsz + LNYw + Ew + YTw);    // 256
    float* DK  = VB + 256;                                 // 1152
    unsigned short* Q0  = (unsigned short*)(DK + 1152);
    unsigned short* qPW1 = Q0;                 // 256*128
    unsigned short* qPW2 = qPW1 + 32768;       // 128*256
    unsigned short* qQKV = qPW2 + 32768;       // 384*128
    unsigned short* qAT  = qQKV + 49152;       // 128*128
    unsigned short* qF1  = qAT  + 16384;       // 2*256*128
    unsigned short* qF2  = qF1  + 65536;       // 2*128*256
    unsigned short* qAG  = qF2  + 65536;       // 2*128*128
    unsigned short* qW3  = qAG  + 32768;       // 128*9*128
    unsigned short* qW13 = qW3  + 147456;      // 169*32*32

    const int NZ = full ? BB : 2;              // batches per dispatch
    const int NH = full ? 1 : 2;               // halves
    unsigned short* E1 = EP;                   // NZ*256*PIX ushorts
    unsigned short* E2 = EP + (size_t)NZ*256*PIX;
    unsigned short* QKV = EP;                  // NZ*384*PIX ushorts (aliased)
    unsigned short* XT  = EP;                  // (B,PIX,128) (aliased)

    dim3 blk(256);

    // ---- merged weight prep (one launch) ----
    wprep_kernel<<<(615424+255)/256, blk, 0, stream>>>(
        proj_w1, proj_w2, qkv_w, attn_ow, ffn_w1, ffn_w2, aggr_w, co_w, plk, Q0);

    // x = conv_ffn(LN(x_in), proj)   [LN pixel-major -> TRANSIN conv]
    ln_t_kernel<<<576, blk, 0, stream>>>(x_in, ln_proj_w, ln_proj_b, LNY);
    for (int h=0; h<NH; ++h) {
        conv1x1_mfma_kernel<unsigned short,true,true,false,true,false><<<dim3(288,2,NZ), blk, 0, stream>>>(
            LNY + (size_t)h*NZ*N1b, qPW1, proj_b1, nullptr, E1, 128);
        dw3x3_bf_kernel<<<NZ*4608, blk, 0, stream>>>(E1, proj_dw, proj_dwb, E2);
        conv1x1_mfma_kernel<unsigned short,false,false,false,false,false><<<dim3(288,1,NZ), blk, 0, stream>>>(
            E2, qPW2, proj_b2, nullptr, RB + (size_t)h*NZ*N1b, 256);
    }

    // x = x + window_attention(LN(x))   [QKV in window-major pixel order]
    ln_t_kernel<<<576, blk, 0, stream>>>(RB, ln_attn_w, ln_attn_b, LNY);
    for (int h=0; h<NH; ++h) {
        conv1x1_mfma_kernel<unsigned short,true,false,false,true,true><<<dim3(288,3,NZ), blk, 0, stream>>>(
            LNY + (size_t)h*NZ*N1b, qQKV, qkv_b, nullptr, QKV, 128);
        attn_mfma_kernel<<<dim3(144,4,NZ), blk, 0, stream>>>(QKV, rpe, LNY + (size_t)h*NZ*N1b);
    }
    conv1x1_mfma_kernel<unsigned short,false,false,true,false,false><<<dim3(288,1,BB), blk, 0, stream>>>(
        LNY, qAT, attn_ob, RB, RB, 128);

    // x lives in RB; y lives in LNY channel-major
    for (int i=0;i<2;++i) {
        const float* fb1 = ffn_b1 + (size_t)i*256;
        const float* fdw = ffn_dw + (size_t)i*256*9;
        const float* fdb = ffn_dwb + (size_t)i*256;
        const float* fb2 = ffn_b2 + (size_t)i*128;
        const float* w1i = pk_w1 + (size_t)i*16*32;
        const float* b1i = pk_b1 + (size_t)i*16;
        const float* w2i = pk_w2 + (size_t)i*288*16;
        const float* b2i = pk_b2 + (size_t)i*288;
        const float* abi = aggr_b + (size_t)i*128;

        for (int h=0; h<NH; ++h) {
            conv1x1_mfma_kernel<float,false,true,false,true,false><<<dim3(288,2,NZ), blk, 0, stream>>>(
                RB + (size_t)h*NZ*N1b, qF1 + (size_t)i*32768, fb1, nullptr, E1, 128);
            dw3x3_bf_kernel<<<NZ*4608, blk, 0, stream>>>(E1, fdw, fdb, E2);
            conv1x1_mfma_kernel<unsigned short,false,false,false,true,false><<<dim3(288,1,NZ), blk, 0, stream>>>(
                E2, qF2 + (size_t)i*32768, fb2, nullptr, LNY + (size_t)h*NZ*N1b, 256);
        }
        t32_kernel<<<576, blk, 0, stream>>>(LNY, YT);
        meanpool_kernel<<<BB*32, blk, 0, stream>>>(LNY, VB);
        mlp_kernel<<<1, blk, 0, stream>>>(VB, w1i, b1i, w2i, b2i, DK);
        conv13_mfma_kernel<<<dim3(6,48,BB), blk, 0, stream>>>(YT, qW13, DK, LNY);
        conv1x1_mfma_kernel<unsigned short,false,false,true,false,false><<<dim3(288,1,BB), blk, 0, stream>>>(
            LNY, qAG + (size_t)i*16384, abi, RB, RB, 128);
    }

    // out = conv3x3(LN(x)) + bias + skip  [transposed LN output]
    ln_t_kernel<<<576, blk, 0, stream>>>(RB, ln_out_w, ln_out_b, XT);
    conv3x3_mfma_kernel<<<dim3(3,192,BB), blk, 0, stream>>>(XT, qW3, co_b, x_in, out);
}

// Round 23
// 1321.082 us; speedup vs baseline: 1.0568x; 1.0087x over previous
//
#include <hip/hip_runtime.h>
#include <cmath>

#define HWD 192
#define PIX (HWD*HWD)      // 36864
#define BB  4
#define CCH 128

using short8 = __attribute__((ext_vector_type(8))) short;
using f32x4  = __attribute__((ext_vector_type(4))) float;

__device__ __forceinline__ float gelu_f(float x) {
    return 0.5f * x * (1.0f + erff(x * 0.70710678118654752f));
}
__device__ __forceinline__ unsigned short f2bf(float f) {
    unsigned int u = __float_as_uint(f);
    u += 0x7fff + ((u >> 16) & 1);          // round-to-nearest-even
    return (unsigned short)(u >> 16);
}
__device__ __forceinline__ float bf2f(unsigned short s) {
    return __uint_as_float((unsigned int)s << 16);
}
__device__ __forceinline__ unsigned pack2bf(float a, float b) {
    return (unsigned)f2bf(a) | ((unsigned)f2bf(b) << 16);
}

// ---------------- LayerNorm: fp32 in, bf16 out TRANSPOSED (B,PIX,128) ----------
__global__ __launch_bounds__(256) void ln_t_kernel(const float* __restrict__ in,
        const float* __restrict__ w, const float* __restrict__ b,
        unsigned short* __restrict__ outT)
{
    int t = blockIdx.x * 256 + threadIdx.x;       // BB*PIX threads
    int bi = t / PIX;
    int p  = t - bi*PIX;
    const float* base = in + (size_t)bi * CCH * PIX + p;
    float v[CCH];
    float s = 0.f;
    #pragma unroll
    for (int c=0;c<CCH;++c) { v[c] = base[(size_t)c*PIX]; s += v[c]; }
    float m = s * (1.f/128.f);
    float q = 0.f;
    #pragma unroll
    for (int c=0;c<CCH;++c) { float d = v[c]-m; q += d*d; }
    float iv = rsqrtf(q*(1.f/128.f) + 1e-6f);
    unsigned short* ob = outT + ((size_t)bi * PIX + p) * 128;
    #pragma unroll
    for (int qq=0; qq<16; ++qq) {
        unsigned short e[8];
        #pragma unroll
        for (int j=0;j<8;++j) {
            int c = qq*8 + j;
            e[j] = f2bf((v[c]-m)*iv*w[c] + b[c]);
        }
        *(uint4*)&ob[qq*8] = *(uint4*)e;
    }
}

// ---------------- transpose y ch 0..31: (B,128,PIX) -> (B,PIX,32) --------------
__global__ __launch_bounds__(256) void t32_kernel(const unsigned short* __restrict__ in,
    unsigned short* __restrict__ outT)
{
    int t = blockIdx.x * 256 + threadIdx.x;       // BB*PIX threads
    int bi = t / PIX;
    int p  = t - bi*PIX;
    const unsigned short* base = in + (size_t)bi * CCH * PIX + p;
    unsigned short e[32];
    #pragma unroll
    for (int c=0;c<32;++c) e[c] = base[(size_t)c*PIX];
    unsigned short* ob = outT + ((size_t)bi * PIX + p) * 32;
    #pragma unroll
    for (int q=0;q<4;++q) *(uint4*)&ob[q*8] = *(uint4*)&e[q*8];
}

// ---------------- 1x1 conv via bf16 MFMA ---------------------------------------
// WINPERM (with TRANSIN): stage pixel perm(wk) so output pixel axis is
// window-major (win*256 + k). 1x1 conv is pixel-permutation invariant.
template<typename TIN, bool TRANSIN, bool DOGELU, bool DORES, bool OBF, bool WINPERM>
__global__ __launch_bounds__(256) void conv1x1_mfma_kernel(
    const TIN* __restrict__ in,
    const unsigned short* __restrict__ wq,   // (Cout, Cin) bf16
    const float* __restrict__ bias,
    const float* __restrict__ res,           // (z, Cout, PIX) fp32 or null
    void* __restrict__ outv,                 // (z, Cout, PIX)
    int Cin)
{
    constexpr int CIP = 72;
    __shared__ unsigned short XL[128*CIP];   // 18,432 B
    const int Cout = gridDim.y * 128;
    const int px0 = blockIdx.x * 128;
    const int co0 = blockIdx.y * 128;
    const size_t bi = blockIdx.z;
    in  += bi * (size_t)Cin * PIX;
    if (DORES) res += bi * (size_t)Cout * PIX;
    float* outf = (float*)outv + bi * (size_t)Cout * PIX;
    unsigned short* outb = (unsigned short*)outv + bi * (size_t)Cout * PIX;
    const int tid = threadIdx.x;
    const int lane = tid & 63, wid = tid >> 6;
    const int wco = (wid >> 1) * 64;
    const int wpx = (wid & 1) * 64;
    const int l15 = lane & 15, l4 = lane >> 4;

    f32x4 acc[4][4];
    #pragma unroll
    for (int i=0;i<4;++i)
        #pragma unroll
        for (int j=0;j<4;++j) acc[i][j] = (f32x4){0.f,0.f,0.f,0.f};

    for (int k0 = 0; k0 < Cin; k0 += 64) {
        __syncthreads();
        if constexpr (TRANSIN) {
            #pragma unroll
            for (int it = 0; it < 4; ++it) {
                int idx = tid + it*256;
                int q = idx & 7, pxl = idx >> 3;
                int src;
                if constexpr (WINPERM) {
                    int wk = px0 + pxl;
                    int win = wk >> 8, k = wk & 255;
                    int wy = win / 12, wxw = win - wy*12;
                    src = ((wy<<4) + (k>>4))*HWD + (wxw<<4) + (k&15);
                } else {
                    src = px0 + pxl;
                }
                const uint4 v = *(const uint4*)((const unsigned short*)in
                                + ((size_t)src)*128 + k0 + q*8);
                *(uint4*)&XL[pxl*CIP + q*8] = v;
            }
        } else {
            #pragma unroll
            for (int it = 0; it < 2; ++it) {
                int idx = tid + it*256;
                int c2  = idx & 31;
                int s   = idx >> 5;
                const TIN* g0 = in + (size_t)(k0 + c2*2    )*PIX + px0 + s*8;
                const TIN* g1 = in + (size_t)(k0 + c2*2 + 1)*PIX + px0 + s*8;
                unsigned short a8[8], b8[8];
                if constexpr (sizeof(TIN) == 2) {
                    *(uint4*)a8 = *(const uint4*)g0;
                    *(uint4*)b8 = *(const uint4*)g1;
                } else {
                    const float4 f0 = *(const float4*)g0;
                    const float4 f1 = *(const float4*)(g0+4);
                    const float4 f2 = *(const float4*)g1;
                    const float4 f3 = *(const float4*)(g1+4);
                    a8[0]=f2bf(f0.x); a8[1]=f2bf(f0.y); a8[2]=f2bf(f0.z); a8[3]=f2bf(f0.w);
                    a8[4]=f2bf(f1.x); a8[5]=f2bf(f1.y); a8[6]=f2bf(f1.z); a8[7]=f2bf(f1.w);
                    b8[0]=f2bf(f2.x); b8[1]=f2bf(f2.y); b8[2]=f2bf(f2.z); b8[3]=f2bf(f2.w);
                    b8[4]=f2bf(f3.x); b8[5]=f2bf(f3.y); b8[6]=f2bf(f3.z); b8[7]=f2bf(f3.w);
                }
                #pragma unroll
                for (int j=0;j<8;++j) {
                    unsigned pk = (unsigned)a8[j] | ((unsigned)b8[j] << 16);
                    *(unsigned*)&XL[(s*8+j)*CIP + c2*2] = pk;
                }
            }
        }
        __syncthreads();
        #pragma unroll
        for (int ks = 0; ks < 2; ++ks) {
            short8 a[4];
            #pragma unroll
            for (int mt=0; mt<4; ++mt) {
                int co = co0 + wco + mt*16 + l15;
                a[mt] = *(const short8*)(wq + (size_t)co*Cin + k0 + ks*32 + l4*8);
            }
            #pragma unroll
            for (int nt=0; nt<4; ++nt) {
                const short8 b = *(const short8*)&XL[(wpx + nt*16 + l15)*CIP + ks*32 + l4*8];
                #pragma unroll
                for (int mt=0; mt<4; ++mt)
                    acc[mt][nt] = __builtin_amdgcn_mfma_f32_16x16x32_bf16(a[mt], b, acc[mt][nt], 0, 0, 0);
            }
        }
    }
    #pragma unroll
    for (int mt=0; mt<4; ++mt) {
        #pragma unroll
        for (int r=0; r<4; ++r) {
            int co = co0 + wco + mt*16 + l4*4 + r;
            float bs = bias[co];
            #pragma unroll
            for (int nt=0; nt<4; ++nt) {
                int px = px0 + wpx + nt*16 + l15;
                float v = acc[mt][nt][r] + bs;
                if (DOGELU) v = gelu_f(v);
                size_t o = (size_t)co*PIX + px;
                if (DORES) v += res[o];
                if (OBF) outb[o] = f2bf(v);
                else     outf[o] = v;
            }
        }
    }
}

// ---------------- 3x3 dense conv 128->128 via bf16 MFMA + bias + skip ----------
__global__ __launch_bounds__(256) void conv3x3_mfma_kernel(
    const unsigned short* __restrict__ inT,  // (B,PIX,128) bf16
    const unsigned short* __restrict__ wq,   // (128,9,128) bf16 [co][tap][ci]
    const float* __restrict__ bias, const float* __restrict__ skip,
    float* __restrict__ out)
{
    constexpr int CIP = 72;
    __shared__ unsigned short XL[4*66*CIP];  // 38,016 B
    const int x0 = blockIdx.x * 64;          // 0..2
    const int y0 = blockIdx.y * 2;           // 0..95
    const int bi = blockIdx.z;
    const int tid = threadIdx.x;
    const int lane = tid & 63, wid = tid >> 6;
    const int wco = (wid >> 1) * 64;
    const int wrow = wid & 1;
    const int l15 = lane & 15, l4 = lane >> 4;
    const unsigned short* inb = inT + (size_t)bi * PIX * 128;

    f32x4 acc[4][4];
    #pragma unroll
    for (int i=0;i<4;++i)
        #pragma unroll
        for (int j=0;j<4;++j) acc[i][j] = (f32x4){0.f,0.f,0.f,0.f};

    for (int ci0 = 0; ci0 < 128; ci0 += 64) {
        __syncthreads();
        #pragma unroll
        for (int it = 0; it < 9; ++it) {
            int idx = tid + it*256;          // 2112 tasks = 264 P x 8 q
            if (idx < 2112) {
                int P = idx >> 3;
                int q = idx & 7;
                int row = P / 66;
                int x = P - row*66;
                int gy = y0 - 1 + row, gx = x0 - 1 + x;
                uint4 v = {0u,0u,0u,0u};
                if ((unsigned)gy < (unsigned)HWD && (unsigned)gx < (unsigned)HWD)
                    v = *(const uint4*)&inb[((size_t)gy*HWD + gx)*128 + ci0 + q*8];
                *(uint4*)&XL[P*CIP + q*8] = v;
            }
        }
        __syncthreads();
        #pragma unroll
        for (int dy=0; dy<3; ++dy) {
            #pragma unroll
            for (int dx=0; dx<3; ++dx) {
                const int rl = wrow + dy;    // 0..3
                #pragma unroll
                for (int ks=0; ks<2; ++ks) {
                    short8 a[4];
                    #pragma unroll
                    for (int mt=0; mt<4; ++mt) {
                        int co = wco + mt*16 + l15;
                        a[mt] = *(const short8*)(wq + ((size_t)co*9 + dy*3+dx)*128 + ci0 + ks*32 + l4*8);
                    }
                    #pragma unroll
                    for (int nt=0; nt<4; ++nt) {
                        const int xl = nt*16 + l15 + dx;   // 0..65
                        const short8 b = *(const short8*)&XL[(rl*66 + xl)*CIP + ks*32 + l4*8];
                        #pragma unroll
                        for (int mt=0; mt<4; ++mt)
                            acc[mt][nt] = __builtin_amdgcn_mfma_f32_16x16x32_bf16(a[mt], b, acc[mt][nt], 0, 0, 0);
                    }
                }
            }
        }
    }
    const int gy = y0 + wrow;
    #pragma unroll
    for (int mt=0; mt<4; ++mt) {
        #pragma unroll
        for (int r=0; r<4; ++r) {
            int co = wco + mt*16 + l4*4 + r;
            float bs = bias[co];
            #pragma unroll
            for (int nt=0; nt<4; ++nt) {
                int gx = x0 + nt*16 + l15;
                size_t o = ((size_t)bi*CCH + co)*PIX + (size_t)gy*HWD + gx;
                out[o] = acc[mt][nt][r] + bs + skip[o];
            }
        }
    }
}

// ---------------- 13x13 dense conv 32->32 pad6 via bf16 MFMA + fused dyn dw3x3 -
// x-tile 32 (LDS 45KB -> 3 blocks/CU for latency hiding)
__global__ __launch_bounds__(256) void conv13_mfma_kernel(
    const unsigned short* __restrict__ YT,   // (B,PIX,32) bf16
    const unsigned short* __restrict__ wq,   // [169][32co][32ci] bf16
    const float* __restrict__ dk,            // [B*32][9]
    unsigned short* __restrict__ outL)       // (B,128,PIX) bf16, ch0..31
{
    __shared__ unsigned short XL[16*44*32];  // 45,056 B, swizzled
    const int x0 = blockIdx.x * 32;          // 0..5
    const int y0 = blockIdx.y * 4;           // 0..47
    const int bi = blockIdx.z;
    const int tid = threadIdx.x;
    const int lane = tid & 63, wr = tid >> 6;
    const int l15 = lane & 15, l4 = lane >> 4;
    const unsigned short* inT = YT + (size_t)bi * PIX * 32;

    #pragma unroll 1
    for (int it = 0; it < 11; ++it) {
        int idx = tid + it*256;              // 0..2815 = 704 P x 4 q
        int P = idx >> 2;
        int q = idx & 3;
        int row = P / 44;
        int x   = P - row*44;
        int gy = y0 - 6 + row, gx = x0 - 6 + x;
        uint4 v = {0u,0u,0u,0u};
        if ((unsigned)gy < (unsigned)HWD && (unsigned)gx < (unsigned)HWD)
            v = *(const uint4*)&inT[((size_t)gy*HWD + gx)*32 + q*8];
        *(uint4*)&XL[P*32 + ((q*8) ^ (((P>>1)&3)<<3))] = v;
    }
    __syncthreads();

    f32x4 acc[2][2];
    #pragma unroll
    for (int i=0;i<2;++i)
        #pragma unroll
        for (int j=0;j<2;++j) acc[i][j] = (f32x4){0.f,0.f,0.f,0.f};

    #pragma unroll 1
    for (int dy=0; dy<13; ++dy) {
        const unsigned short* wrow = wq + (size_t)dy*13*1024;
        #pragma unroll
        for (int dx=0; dx<13; ++dx) {
            const short8 a0 = *(const short8*)(wrow + dx*1024 + l15*32 + l4*8);
            const short8 a1 = *(const short8*)(wrow + dx*1024 + (16+l15)*32 + l4*8);
            #pragma unroll
            for (int nt=0; nt<2; ++nt) {
                const int P = (wr + dy)*44 + nt*16 + l15 + dx;
                const short8 b = *(const short8*)&XL[P*32 + ((l4*8) ^ (((P>>1)&3)<<3))];
                acc[0][nt] = __builtin_amdgcn_mfma_f32_16x16x32_bf16(a0, b, acc[0][nt], 0, 0, 0);
                acc[1][nt] = __builtin_amdgcn_mfma_f32_16x16x32_bf16(a1, b, acc[1][nt], 0, 0, 0);
            }
        }
    }
    const int gy = y0 + wr;
    #pragma unroll
    for (int mt=0; mt<2; ++mt) {
        #pragma unroll
        for (int r=0; r<4; ++r) {
            const int co = mt*16 + l4*4 + r;
            const float* dkk = dk + (bi*32 + co)*9;
            float k0=dkk[0],k1=dkk[1],k2=dkk[2],k3=dkk[3],k4=dkk[4],
                  k5=dkk[5],k6=dkk[6],k7=dkk[7],k8=dkk[8];
            #pragma unroll
            for (int nt=0; nt<2; ++nt) {
                const int px = nt*16 + l15;
                float dsum = 0.f;
                #pragma unroll
                for (int e=0; e<9; ++e) {
                    int ey = e/3, ex = e - ey*3;
                    int P = (wr+5+ey)*44 + px+5+ex;
                    float pv = bf2f(XL[P*32 + (co ^ (((P>>1)&3)<<3))]);
                    float kk = (e==0?k0:e==1?k1:e==2?k2:e==3?k3:e==4?k4:e==5?k5:e==6?k6:e==7?k7:k8);
                    dsum += pv * kk;
                }
                float v = acc[mt][nt][r] + dsum;
                outL[((size_t)bi*CCH + co)*PIX + (size_t)gy*HWD + x0 + px] = f2bf(v);
            }
        }
    }
}

// ---------------- depthwise 3x3 pad1 + bias, bf16 in/out, 8 px/thread ----------
__global__ __launch_bounds__(256) void dw3x3_bf_kernel(const unsigned short* __restrict__ in,
    const float* __restrict__ w, const float* __restrict__ b,
    unsigned short* __restrict__ out)
{
    int t = blockIdx.x*256 + threadIdx.x;     // nb*256*PIX/8 threads
    int pc = t / (PIX/8);
    int p8 = (t - pc*(PIX/8)) * 8;
    int c = pc & 255;
    int y = p8 / HWD, x0 = p8 - y*HWD;        // x0 multiple of 8 -> 16B aligned
    const unsigned short* ib = in + (size_t)pc * PIX;
    float wk[9];
    #pragma unroll
    for (int e=0;e<9;++e) wk[e] = w[c*9+e];
    float bc = b[c];
    float a[8];
    #pragma unroll
    for (int j=0;j<8;++j) a[j] = bc;
    float cen[8];
    #pragma unroll
    for (int ky=0;ky<3;++ky) {
        int yy = y + ky - 1;
        if ((unsigned)yy < (unsigned)HWD) {
            const unsigned short* row = ib + (size_t)yy*HWD;
            unsigned short e8[8];
            *(uint4*)e8 = *(const uint4*)&row[x0];
            float v[10];
            v[0] = (x0 > 0) ? bf2f(row[x0-1]) : 0.f;
            #pragma unroll
            for (int j=0;j<8;++j) v[j+1] = bf2f(e8[j]);
            v[9] = (x0 + 8 < HWD) ? bf2f(row[x0+8]) : 0.f;
            if (ky == 1) {
                #pragma unroll
                for (int j=0;j<8;++j) cen[j] = v[j+1];
            }
            const float w0 = wk[ky*3+0], w1 = wk[ky*3+1], w2 = wk[ky*3+2];
            #pragma unroll
            for (int j=0;j<8;++j)
                a[j] += v[j]*w0 + v[j+1]*w1 + v[j+2]*w2;
        } else if (ky == 1) {
            #pragma unroll
            for (int j=0;j<8;++j) cen[j] = 0.f;   // unreachable (y always valid)
        }
    }
    unsigned short r[8];
    #pragma unroll
    for (int j=0;j<8;++j) r[j] = f2bf(gelu_f(a[j]) + cen[j]);
    *(uint4*)(out + (size_t)pc*PIX + p8) = *(uint4*)r;
}

// ---------------- window attention via bf16 MFMA (win-major QKV) ---------------
__global__ __launch_bounds__(256) void attn_mfma_kernel(
    const unsigned short* __restrict__ qkv,  // (z, 384, 144*256) bf16 win-major
    const float* __restrict__ table,         // (4, 961) f32
    unsigned short* __restrict__ o)          // (z, 128, PIX) bf16 pixel-major
{
    __shared__ unsigned short KL[256*44];    // [k][c] pad44 (22,528 B)
    __shared__ unsigned short VL[32*264];    // [d][k] pad264 (16,896 B)
    __shared__ unsigned short PL[4*16*40];   // per-wave P k-tile (5,120 B)
    __shared__ float BT[961];
    __shared__ unsigned short OL[64*33];     // [q][d] pad33 (4,224 B)
    const int win = blockIdx.x, head = blockIdx.y;
    const int bi2 = blockIdx.z;
    const int wy = win/12, wx = win - wy*12;
    const int wb = win << 8;                 // win*256
    qkv += (size_t)bi2 * 384 * PIX;
    o   += (size_t)bi2 * CCH * PIX;
    const unsigned short* qb = qkv + (size_t)(head*32) * PIX;
    const unsigned short* kb = qkv + (size_t)(128 + head*32) * PIX;
    const unsigned short* vb = qkv + (size_t)(256 + head*32) * PIX;
    const int tid = threadIdx.x;

    // V: [d][k] direct uint4 copies (dense)
    #pragma unroll
    for (int it = 0; it < 4; ++it) {
        int idx = tid + it*256;
        int c = idx & 31, seg = idx >> 5;
        int k0 = seg*8;
        *(uint4*)&VL[c*264 + k0] = *(const uint4*)&vb[(size_t)c*PIX + wb + k0];
    }
    // K: uint4 global load (8 consecutive k for one c), scalar LDS transpose
    #pragma unroll
    for (int it = 0; it < 4; ++it) {
        int idx = tid + it*256;
        int c = idx & 31, seg = idx >> 5;
        int k0 = seg*8;
        unsigned short e[8];
        *(uint4*)e = *(const uint4*)&kb[(size_t)c*PIX + wb + k0];
        #pragma unroll
        for (int j=0;j<8;++j) KL[(k0+j)*44 + c] = e[j];
    }
    for (int i = tid; i < 961; i += 256) BT[i] = table[head*961 + i];
    __syncthreads();

    const int lane = tid & 63, w = tid >> 6;
    const int l15 = lane & 15, l4 = lane >> 4;
    const float scale = 0.17677669529663687f;   // 32^-0.5
    unsigned short* PLw = &PL[w*16*40];

    #pragma unroll 1
    for (int qc = 0; qc < 4; ++qc) {
        const int qi = qc*64 + w*16 + l15;
        const int iy = qi >> 4, ix = qi & 15;

        short8 qf;
        #pragma unroll
        for (int j=0;j<8;++j) qf[j] = (short)qb[(size_t)(l4*8+j)*PIX + wb + qi];

        f32x4 s[16];
        #pragma unroll
        for (int nt=0; nt<16; ++nt) {
            const short8 a = *(const short8*)&KL[(nt*16 + l15)*44 + l4*8];
            s[nt] = __builtin_amdgcn_mfma_f32_16x16x32_bf16(a, qf, (f32x4){0.f,0.f,0.f,0.f}, 0, 0, 0);
        }

        float m = -1e30f;
        #pragma unroll
        for (int nt=0; nt<16; ++nt) {
            #pragma unroll
            for (int r=0; r<4; ++r) {
                int k = nt*16 + l4*4 + r;
                float bv = BT[((k>>4) - iy + 15)*31 + ((k&15) - ix + 15)];
                float v = s[nt][r]*scale + bv;
                s[nt][r] = v;
                m = fmaxf(m, v);
            }
        }
        m = fmaxf(m, __shfl_xor(m, 16, 64));
        m = fmaxf(m, __shfl_xor(m, 32, 64));
        float l = 0.f;
        #pragma unroll
        for (int nt=0; nt<16; ++nt) {
            #pragma unroll
            for (int r=0; r<4; ++r) {
                float p = __expf(s[nt][r] - m);
                s[nt][r] = p;
                l += p;
            }
        }
        l += __shfl_xor(l, 16, 64);
        l += __shfl_xor(l, 32, 64);

        // PV: per 32-k tile, write P tile to per-wave LDS then consume
        f32x4 o0 = (f32x4){0.f,0.f,0.f,0.f}, o1 = (f32x4){0.f,0.f,0.f,0.f};
        #pragma unroll
        for (int kt=0; kt<8; ++kt) {
            #pragma unroll
            for (int h=0; h<2; ++h) {
                int nt = kt*2 + h;
                *(unsigned*)&PLw[l15*40 + h*16 + l4*4]     = pack2bf(s[nt][0], s[nt][1]);
                *(unsigned*)&PLw[l15*40 + h*16 + l4*4 + 2] = pack2bf(s[nt][2], s[nt][3]);
            }
            const short8 pa = *(const short8*)&PLw[l15*40 + l4*8];
            const short8 v0 = *(const short8*)&VL[l15*264 + kt*32 + l4*8];
            const short8 v1 = *(const short8*)&VL[(16+l15)*264 + kt*32 + l4*8];
            o0 = __builtin_amdgcn_mfma_f32_16x16x32_bf16(pa, v0, o0, 0, 0, 0);
            o1 = __builtin_amdgcn_mfma_f32_16x16x32_bf16(pa, v1, o1, 0, 0, 0);
        }

        #pragma unroll
        for (int r=0; r<4; ++r) {
            float lr = __shfl(l, l4*4 + r, 64);
            float inv = 1.f / lr;
            OL[(w*16 + l4*4 + r)*33 + l15]      = f2bf(o0[r]*inv);
            OL[(w*16 + l4*4 + r)*33 + 16 + l15] = f2bf(o1[r]*inv);
        }
        __syncthreads();

        // pixel-major output store (dense uint4)
        const int d = tid >> 3, seg = tid & 7;
        const int q0l = seg*8;
        const int qi0 = qc*64 + q0l;
        const int sp0 = ((wy<<4) + (qi0>>4))*HWD + (wx<<4) + (qi0 & 15);
        unsigned short tmp[8];
        #pragma unroll
        for (int j=0;j<8;++j) tmp[j] = OL[(q0l+j)*33 + d];
        *(uint4*)&o[(size_t)(head*32 + d)*PIX + sp0] = *(uint4*)tmp;
        __syncthreads();
    }
}

// ---------------- mean over spatial for channels 0..31 (bf16 in) ---------------
__global__ __launch_bounds__(256) void meanpool_kernel(const unsigned short* __restrict__ in,
    float* __restrict__ v)
{
    int bc = blockIdx.x;               // BB*32
    int bi = bc >> 5, c = bc & 31;
    const unsigned short* base = in + ((size_t)bi*CCH + c) * PIX;
    float s = 0.f;
    for (int i = threadIdx.x; i < PIX/4; i += 256) {
        const uint2 t4 = ((const uint2*)base)[i];
        s += bf2f((unsigned short)(t4.x & 0xffff)) + bf2f((unsigned short)(t4.x >> 16))
           + bf2f((unsigned short)(t4.y & 0xffff)) + bf2f((unsigned short)(t4.y >> 16));
    }
    #pragma unroll
    for (int off=32; off>0; off>>=1) s += __shfl_down(s, off, 64);
    __shared__ float red[4];
    if ((threadIdx.x & 63) == 0) red[threadIdx.x >> 6] = s;
    __syncthreads();
    if (threadIdx.x == 0) v[bc] = (red[0]+red[1]+red[2]+red[3]) * (1.f/PIX);
}

// ---------------- tiny MLP producing dynamic 3x3 kernels -----------------------
__global__ __launch_bounds__(256) void mlp_kernel(const float* __restrict__ v,
    const float* __restrict__ pw1, const float* __restrict__ pb1,
    const float* __restrict__ pw2, const float* __restrict__ pb2,
    float* __restrict__ dk)
{
    __shared__ float h[64];
    int tid = threadIdx.x;
    if (tid < 64) {
        int bi = tid >> 4, m = tid & 15;
        float s = pb1[m];
        for (int c=0;c<32;++c) s += v[bi*32+c]*pw1[m*32+c];
        h[tid] = gelu_f(s);
    }
    __syncthreads();
    for (int idx = tid; idx < BB*288; idx += 256) {
        int bi = idx / 288, j = idx - bi*288;
        float s = pb2[j];
        for (int m=0;m<16;++m) s += h[bi*16+m]*pw2[j*16+m];
        dk[idx] = s;
    }
}

// ---------------- merged weight prep (all casts + relayouts, one launch) -------
__global__ __launch_bounds__(256) void wprep_kernel(
    const float* __restrict__ proj_w1, const float* __restrict__ proj_w2,
    const float* __restrict__ qkv_w,   const float* __restrict__ attn_ow,
    const float* __restrict__ ffn_w1,  const float* __restrict__ ffn_w2,
    const float* __restrict__ aggr_w,  const float* __restrict__ co_w,
    const float* __restrict__ plk,     unsigned short* __restrict__ Q0)
{
    int idx = blockIdx.x*256 + threadIdx.x;
    if (idx < 32768) { Q0[idx] = f2bf(proj_w1[idx]); return; }
    idx -= 32768;
    if (idx < 32768) { Q0[32768 + idx] = f2bf(proj_w2[idx]); return; }
    idx -= 32768;
    if (idx < 49152) { Q0[65536 + idx] = f2bf(qkv_w[idx]); return; }
    idx -= 49152;
    if (idx < 16384) { Q0[114688 + idx] = f2bf(attn_ow[idx]); return; }
    idx -= 16384;
    if (idx < 65536) { Q0[131072 + idx] = f2bf(ffn_w1[idx]); return; }
    idx -= 65536;
    if (idx < 65536) { Q0[196608 + idx] = f2bf(ffn_w2[idx]); return; }
    idx -= 65536;
    if (idx < 32768) { Q0[262144 + idx] = f2bf(aggr_w[idx]); return; }
    idx -= 32768;
    if (idx < 147456) {          // co_w (128,128,3,3) -> [co][tap][ci]
        int co = idx / (128*9);
        int rem = idx - co*128*9;
        int ci = rem / 9;
        int tap = rem - ci*9;
        Q0[294912 + ((size_t)co*9 + tap)*128 + ci] = f2bf(co_w[idx]);
        return;
    }
    idx -= 147456;
    if (idx < 173056) {          // plk (32,32,13,13) -> [tap][co][ci]
        int co = idx / (32*169);
        int rem = idx - co*32*169;
        int ci = rem / 169;
        int tap = rem - ci*169;
        Q0[442368 + ((size_t)tap*32 + co)*32 + ci] = f2bf(plk[idx]);
    }
}

extern "C" void kernel_launch(void* const* d_in, const int* in_sizes, int n_in,
                              void* d_out, int out_size, void* d_ws, size_t ws_size,
                              hipStream_t stream) {
    (void)in_sizes; (void)n_in; (void)out_size;
    const float* x_in      = (const float*)d_in[0];
    const float* plk       = (const float*)d_in[1];
    const float* ln_proj_w = (const float*)d_in[2];
    const float* ln_proj_b = (const float*)d_in[3];
    const float* proj_w1   = (const float*)d_in[4];
    const float* proj_b1   = (const float*)d_in[5];
    const float* proj_dw   = (const float*)d_in[6];
    const float* proj_dwb  = (const float*)d_in[7];
    const float* proj_w2   = (const float*)d_in[8];
    const float* proj_b2   = (const float*)d_in[9];
    const float* ln_attn_w = (const float*)d_in[10];
    const float* ln_attn_b = (const float*)d_in[11];
    const float* qkv_w     = (const float*)d_in[12];
    const float* qkv_b     = (const float*)d_in[13];
    const float* attn_ow   = (const float*)d_in[14];
    const float* attn_ob   = (const float*)d_in[15];
    const float* rpe       = (const float*)d_in[16];
    const float* ffn_w1    = (const float*)d_in[17];
    const float* ffn_b1    = (const float*)d_in[18];
    const float* ffn_dw    = (const float*)d_in[19];
    const float* ffn_dwb   = (const float*)d_in[20];
    const float* ffn_w2    = (const float*)d_in[21];
    const float* ffn_b2    = (const float*)d_in[22];
    const float* pk_w1     = (const float*)d_in[23];
    const float* pk_b1     = (const float*)d_in[24];
    const float* pk_w2     = (const float*)d_in[25];
    const float* pk_b2     = (const float*)d_in[26];
    const float* aggr_w    = (const float*)d_in[27];
    const float* aggr_b    = (const float*)d_in[28];
    const float* ln_out_w  = (const float*)d_in[29];
    const float* ln_out_b  = (const float*)d_in[30];
    const float* co_w      = (const float*)d_in[31];
    const float* co_b      = (const float*)d_in[32];
    float* out = (float*)d_out;

    const size_t N1b = (size_t)CCH * PIX;          // elems per batch (128ch)
    const size_t RBsz = (size_t)BB * N1b;          // 18,874,368 fl
    const size_t LNYw = RBsz / 2;                  // bf16 (B,128,PIX) in fl-words
    const size_t YTw  = (size_t)BB*PIX*32/2;       // 2,359,296 fl
    const size_t QTOT = 615424;                    // bf16 weight elems (ushort)
    const size_t TAILw = 256 + 1152 + QTOT/2 + 64; // VB+DK+weights (fl)
    const size_t need_half = RBsz + LNYw + RBsz   + YTw + TAILw;
    const size_t need_full = RBsz + LNYw + 2*RBsz + YTw + TAILw;
    if (ws_size < need_half * sizeof(float)) return;   // diagnostic guard
    const bool full = ws_size >= need_full * sizeof(float);
    const size_t Ew = full ? 2*RBsz : RBsz;        // E-pool size in fl

    float* ws  = (float*)d_ws;
    float* RB  = ws;                               // fp32 residual x
    unsigned short* LNY  = (unsigned short*)(RB + RBsz);   // bf16
    unsigned short* EP   = (unsigned short*)(RB + RBsz + LNYw);    // E pool
    unsigned short* YT   = (unsigned short*)(RB + RBsz + LNYw + Ew);
    float* VB  = (float*)(RB + RBsz + LNYw + Ew + YTw);    // 256
    float* DK  = VB + 256;                                 // 1152
    unsigned short* Q0  = (unsigned short*)(DK + 1152);
    unsigned short* qPW1 = Q0;                 // 256*128
    unsigned short* qPW2 = qPW1 + 32768;       // 128*256
    unsigned short* qQKV = qPW2 + 32768;       // 384*128
    unsigned short* qAT  = qQKV + 49152;       // 128*128
    unsigned short* qF1  = qAT  + 16384;       // 2*256*128
    unsigned short* qF2  = qF1  + 65536;       // 2*128*256
    unsigned short* qAG  = qF2  + 65536;       // 2*128*128
    unsigned short* qW3  = qAG  + 32768;       // 128*9*128
    unsigned short* qW13 = qW3  + 147456;      // 169*32*32

    const int NZ = full ? BB : 2;              // batches per dispatch
    const int NH = full ? 1 : 2;               // halves
    unsigned short* E1 = EP;                   // NZ*256*PIX ushorts
    unsigned short* E2 = EP + (size_t)NZ*256*PIX;
    unsigned short* QKV = EP;                  // NZ*384*PIX ushorts (aliased)
    unsigned short* XT  = EP;                  // (B,PIX,128) (aliased)

    dim3 blk(256);

    // ---- merged weight prep (one launch) ----
    wprep_kernel<<<(615424+255)/256, blk, 0, stream>>>(
        proj_w1, proj_w2, qkv_w, attn_ow, ffn_w1, ffn_w2, aggr_w, co_w, plk, Q0);

    // x = conv_ffn(LN(x_in), proj)   [LN pixel-major -> TRANSIN conv]
    ln_t_kernel<<<576, blk, 0, stream>>>(x_in, ln_proj_w, ln_proj_b, LNY);
    for (int h=0; h<NH; ++h) {
        conv1x1_mfma_kernel<unsigned short,true,true,false,true,false><<<dim3(288,2,NZ), blk, 0, stream>>>(
            LNY + (size_t)h*NZ*N1b, qPW1, proj_b1, nullptr, E1, 128);
        dw3x3_bf_kernel<<<NZ*4608, blk, 0, stream>>>(E1, proj_dw, proj_dwb, E2);
        conv1x1_mfma_kernel<unsigned short,false,false,false,false,false><<<dim3(288,1,NZ), blk, 0, stream>>>(
            E2, qPW2, proj_b2, nullptr, RB + (size_t)h*NZ*N1b, 256);
    }

    // x = x + window_attention(LN(x))   [QKV in window-major pixel order]
    ln_t_kernel<<<576, blk, 0, stream>>>(RB, ln_attn_w, ln_attn_b, LNY);
    for (int h=0; h<NH; ++h) {
        conv1x1_mfma_kernel<unsigned short,true,false,false,true,true><<<dim3(288,3,NZ), blk, 0, stream>>>(
            LNY + (size_t)h*NZ*N1b, qQKV, qkv_b, nullptr, QKV, 128);
        attn_mfma_kernel<<<dim3(144,4,NZ), blk, 0, stream>>>(QKV, rpe, LNY + (size_t)h*NZ*N1b);
    }
    conv1x1_mfma_kernel<unsigned short,false,false,true,false,false><<<dim3(288,1,BB), blk, 0, stream>>>(
        LNY, qAT, attn_ob, RB, RB, 128);

    // x lives in RB; y lives in LNY channel-major
    for (int i=0;i<2;++i) {
        const float* fb1 = ffn_b1 + (size_t)i*256;
        const float* fdw = ffn_dw + (size_t)i*256*9;
        const float* fdb = ffn_dwb + (size_t)i*256;
        const float* fb2 = ffn_b2 + (size_t)i*128;
        const float* w1i = pk_w1 + (size_t)i*16*32;
        const float* b1i = pk_b1 + (size_t)i*16;
        const float* w2i = pk_w2 + (size_t)i*288*16;
        const float* b2i = pk_b2 + (size_t)i*288;
        const float* abi = aggr_b + (size_t)i*128;

        for (int h=0; h<NH; ++h) {
            conv1x1_mfma_kernel<float,false,true,false,true,false><<<dim3(288,2,NZ), blk, 0, stream>>>(
                RB + (size_t)h*NZ*N1b, qF1 + (size_t)i*32768, fb1, nullptr, E1, 128);
            dw3x3_bf_kernel<<<NZ*4608, blk, 0, stream>>>(E1, fdw, fdb, E2);
            conv1x1_mfma_kernel<unsigned short,false,false,false,true,false><<<dim3(288,1,NZ), blk, 0, stream>>>(
                E2, qF2 + (size_t)i*32768, fb2, nullptr, LNY + (size_t)h*NZ*N1b, 256);
        }
        t32_kernel<<<576, blk, 0, stream>>>(LNY, YT);
        meanpool_kernel<<<BB*32, blk, 0, stream>>>(LNY, VB);
        mlp_kernel<<<1, blk, 0, stream>>>(VB, w1i, b1i, w2i, b2i, DK);
        conv13_mfma_kernel<<<dim3(6,48,BB), blk, 0, stream>>>(YT, qW13, DK, LNY);
        conv1x1_mfma_kernel<unsigned short,false,false,true,false,false><<<dim3(288,1,BB), blk, 0, stream>>>(
            LNY, qAG + (size_t)i*16384, abi, RB, RB, 128);
    }

    // out = conv3x3(LN(x)) + bias + skip  [transposed LN output]
    ln_t_kernel<<<576, blk, 0, stream>>>(RB, ln_out_w, ln_out_b, XT);
    conv3x3_mfma_kernel<<<dim3(3,96,BB), blk, 0, stream>>>(XT, qW3, co_b, x_in, out);
}